// Round 11
// baseline (331.773 us; speedup 1.0000x reference)
//
#include <hip/hip_runtime.h>
#include <hip/hip_bf16.h>

typedef __bf16 bf16_t;
typedef bf16_t bf16x2 __attribute__((ext_vector_type(2)));
typedef bf16_t bf16x8 __attribute__((ext_vector_type(8)));
typedef float f32x4 __attribute__((ext_vector_type(4)));

#define DEVI __device__ __forceinline__

DEVI void gld_lds16(const void* g, void* l) {
  __builtin_amdgcn_global_load_lds(
      (const __attribute__((address_space(1))) void*)g,
      (__attribute__((address_space(3))) void*)l, 16, 0, 0);
}

DEVI bf16x8 cvt8(f32x4 a, f32x4 b) {
  return bf16x8{(__bf16)a[0], (__bf16)a[1], (__bf16)a[2], (__bf16)a[3],
                (__bf16)b[0], (__bf16)b[1], (__bf16)b[2], (__bf16)b[3]};
}

// ---------------------------------------------------------------------------
// f32 -> bf16 conversion, 8 elements/thread.
// ---------------------------------------------------------------------------
__global__ __launch_bounds__(256) void cvt_f32_bf16(
    const float* __restrict__ in, bf16_t* __restrict__ out, long n) {
  long i = ((long)blockIdx.x * 256 + threadIdx.x) * 8;
  if (i >= n) return;
  float4 a = *(const float4*)(in + i);
  float4 b = *(const float4*)(in + i + 4);
  bf16x8 v = {(__bf16)a.x, (__bf16)a.y, (__bf16)a.z, (__bf16)a.w,
              (__bf16)b.x, (__bf16)b.y, (__bf16)b.z, (__bf16)b.w};
  *(bf16x8*)(out + i) = v;
}

// ---------------------------------------------------------------------------
// Round-6-validated 128 x (64*FC) all-bf16 GEMM (92 us QKV @ FC=3, grid 512).
// 8 waves (2M x 4N), BK=64, LDS double-buffered, XOR swizzle (16B slot ^
// row&7) via pre-swizzled global source + linear LDS dest (global_load_lds).
// Staging ledger: prologue T0.A+T0.B+T1.A vmcnt(2); t.p1 stage T+1.B (other
// buf); t.p2 stage T+2.A (cur buf); gate vmcnt(2) at p2, tail vmcnt(0).
// XCD supertiling 2x4 chunks.  Requires grid==nM*nN, nM%2==0, nN%4==0.
// ---------------------------------------------------------------------------
template <int FC, int MINW, typename CT>
__global__ __launch_bounds__(512, MINW) void gemm128(
    const bf16_t* __restrict__ A, const bf16_t* __restrict__ W,
    CT* __restrict__ C, int M, int N, int K) {
  constexpr int BN = FC * 64;
  constexpr int P1 = FC / 2, P2 = FC - P1;
  __shared__ __align__(16) bf16_t As[2][128 * 64];
  __shared__ __align__(16) bf16_t Bs[2][BN * 64];
  const int tid = threadIdx.x, wave = tid >> 6, lane = tid & 63;
  const int q16 = lane & 15, gq = lane >> 4, sw = q16 & 7;
  const int wm = wave >> 2, wn = wave & 3;
  const int nM = M >> 7, nN = N / BN;
  const int cM = nM >> 1, cN = nN >> 2;
  const int xcd = (int)blockIdx.x & 7, wi = (int)blockIdx.x >> 3;
  const int tm = ((xcd >> 2) * cM + wi / cN) << 7;
  const int tn = ((xcd & 3) * cN + wi % cN) * BN;
  const int NT = K >> 6;
  const bf16_t* Ag = A + (size_t)tm * K;
  const bf16_t* Wg = W + (size_t)tn * K;
  const int sr = (wave << 3) + (lane >> 3);
  const int scol = (((lane & 7) ^ (sr & 7)) << 3);

#define STG(gbase, kq, uu, ldsbuf)                              \
  gld_lds16((gbase) + (size_t)((uu)*64 + sr) * K + (kq) + scol, \
            &(ldsbuf)[0] + (uu)*4096 + (wave << 9))

  f32x4 acc[4][FC];
#pragma unroll
  for (int i = 0; i < 4; ++i)
#pragma unroll
    for (int j = 0; j < FC; ++j) acc[i][j] = f32x4{0.f, 0.f, 0.f, 0.f};

  STG(Ag, 0, 0, As[0]);
  STG(Ag, 0, 1, As[0]);
#pragma unroll
  for (int u = 0; u < FC; ++u) STG(Wg, 0, u, Bs[0]);
  STG(Ag, 64, 0, As[1]);
  STG(Ag, 64, 1, As[1]);
  asm volatile("s_waitcnt vmcnt(2)" ::: "memory");
  __builtin_amdgcn_s_barrier();

  for (int t = 0; t < NT; ++t) {
    const int cur = t & 1;
    const bf16_t* Acur = As[cur];
    const bf16_t* Bcur = Bs[cur];
    const int k1 = (t + 1) << 6, k2 = (t + 2) << 6;
    bf16x8 afr[4][2];

#pragma unroll
    for (int fr = 0; fr < 4; ++fr) {
      const bf16_t* rp = Acur + (wm * 64 + fr * 16 + q16) * 64;
      afr[fr][0] = *(const bf16x8*)(rp + ((gq ^ sw) << 3));
      afr[fr][1] = *(const bf16x8*)(rp + (((4 + gq) ^ sw) << 3));
    }
    bf16x8 b1[P1][2];
#pragma unroll
    for (int fc = 0; fc < P1; ++fc) {
      const bf16_t* rp = Bcur + (wn * (16 * FC) + fc * 16 + q16) * 64;
      b1[fc][0] = *(const bf16x8*)(rp + ((gq ^ sw) << 3));
      b1[fc][1] = *(const bf16x8*)(rp + (((4 + gq) ^ sw) << 3));
    }
    if (t + 1 < NT) {
#pragma unroll
      for (int u = 0; u < FC; ++u) STG(Wg, k1, u, Bs[cur ^ 1]);
    }
    __builtin_amdgcn_s_barrier();
    __builtin_amdgcn_s_setprio(1);
#pragma unroll
    for (int fr = 0; fr < 4; ++fr)
#pragma unroll
      for (int fc = 0; fc < P1; ++fc)
#pragma unroll
        for (int kk = 0; kk < 2; ++kk)
          acc[fr][fc] = __builtin_amdgcn_mfma_f32_16x16x32_bf16(
              afr[fr][kk], b1[fc][kk], acc[fr][fc], 0, 0, 0);
    __builtin_amdgcn_s_setprio(0);
    asm volatile("" ::: "memory");
    __builtin_amdgcn_s_barrier();

    bf16x8 b2[P2][2];
#pragma unroll
    for (int f2 = 0; f2 < P2; ++f2) {
      const bf16_t* rp = Bcur + (wn * (16 * FC) + (P1 + f2) * 16 + q16) * 64;
      b2[f2][0] = *(const bf16x8*)(rp + ((gq ^ sw) << 3));
      b2[f2][1] = *(const bf16x8*)(rp + (((4 + gq) ^ sw) << 3));
    }
    if (t + 2 < NT) {
      STG(Ag, k2, 0, As[cur]);
      STG(Ag, k2, 1, As[cur]);
    }
    __builtin_amdgcn_s_barrier();
    __builtin_amdgcn_s_setprio(1);
#pragma unroll
    for (int fr = 0; fr < 4; ++fr)
#pragma unroll
      for (int f2 = 0; f2 < P2; ++f2)
#pragma unroll
        for (int kk = 0; kk < 2; ++kk)
          acc[fr][P1 + f2] = __builtin_amdgcn_mfma_f32_16x16x32_bf16(
              afr[fr][kk], b2[f2][kk], acc[fr][P1 + f2], 0, 0, 0);
    __builtin_amdgcn_s_setprio(0);
    if (t + 2 < NT)
      asm volatile("s_waitcnt vmcnt(2)" ::: "memory");
    else
      asm volatile("s_waitcnt vmcnt(0)" ::: "memory");
    __builtin_amdgcn_s_barrier();
  }

#pragma unroll
  for (int fr = 0; fr < 4; ++fr)
#pragma unroll
    for (int fc = 0; fc < FC; ++fc)
#pragma unroll
      for (int i = 0; i < 4; ++i) {
        int row = tm + wm * 64 + fr * 16 + gq * 4 + i;
        int col = tn + wn * (16 * FC) + fc * 16 + q16;
        C[(size_t)row * N + col] = (CT)acc[fr][fc][i];
      }
#undef STG
}

// ---------------------------------------------------------------------------
// gemmf2: fused-convert 128x128 GEMM, fully compiler-tracked staging.
// A (bf16) and W (f32) both reg-staged with plain vector loads; W uses
// 2-deep ping-pong register sets so loads issued at tile t are consumed at
// tile t+1's p1b (a full K-tile of latency hiding, no explicit vmcnt).
// LDS XOR-swizzled via linear global source + swizzled ds_write address;
// reads use the same swizzle.  Per K-tile t (2 barriers):
//   p1 : issue T+2.A -> areg, T+2.B -> brg[t&1]; ds_read afr + b1;
//        lgkmcnt(0); barA
//   p1b: MFMA1; ds_write T+1.B from brg[(t+1)&1] -> Bs[cur^1];
//        ds_write T+2.A from areg -> As[cur]    (compiler waits the regs)
//   p2 : ds_read b2; MFMA2; lgkmcnt(0); barC
// Ledger: As[cur] writes follow barA (own reads lgkm-drained before it);
// Bs[cur^1] last read at t-1.p2 before barC(t-1); all ds_writes published
// by lgkmcnt(0)+barC before any reader.  Grid <= 512 (2 blocks/CU, 64KB).
// ---------------------------------------------------------------------------
template <typename CT>
__global__ __launch_bounds__(512, 4) void gemmf2(
    const bf16_t* __restrict__ Ab, const float* __restrict__ Wf,
    CT* __restrict__ C, int M, int N, int K) {
  constexpr int FC = 2;
  __shared__ __align__(16) bf16_t As[2][128 * 64];
  __shared__ __align__(16) bf16_t Bs[2][128 * 64];
  const int tid = threadIdx.x, wave = tid >> 6, lane = tid & 63;
  const int q16 = lane & 15, gq = lane >> 4, sw = q16 & 7;
  const int wm = wave >> 2, wn = wave & 3;
  const int nM = M >> 7, nN = N >> 7;
  const int cM = nM >> 1, cN = nN >> 2;
  const int xcd = (int)blockIdx.x & 7, wi = (int)blockIdx.x >> 3;
  const int tm = ((xcd >> 2) * cM + wi / cN) << 7;
  const int tn = ((xcd & 3) * cN + wi % cN) << 7;
  const int NT = K >> 6;
  const bf16_t* Ag = Ab + (size_t)tm * K;
  const float* Wg = Wf + (size_t)tn * K;
  const int sr = (wave << 3) + (lane >> 3);
  const int c8 = (lane & 7) * 8;  // linear col (elements)
  const int ldsoff = sr * 64 + (((lane & 7) ^ (sr & 7)) << 3);

  f32x4 acc[4][FC];
#pragma unroll
  for (int i = 0; i < 4; ++i)
#pragma unroll
    for (int j = 0; j < FC; ++j) acc[i][j] = f32x4{0.f, 0.f, 0.f, 0.f};

  f32x4 brg[2][FC][2];  // 2-deep ping-pong B staging
  bf16x8 areg[2];       // 1-deep A staging

#define AISS(kq)                                                          \
  {                                                                       \
    _Pragma("unroll") for (int u = 0; u < 2; ++u) areg[u] =               \
        *(const bf16x8*)(Ag + (size_t)(u * 64 + sr) * K + (kq) + c8);     \
  }
#define AWR(buf)                                                          \
  {                                                                       \
    _Pragma("unroll") for (int u = 0; u < 2; ++u)                         \
        *(bf16x8*)(&As[buf][0] + u * 4096 + ldsoff) = areg[u];            \
  }
#define BISS(kq, s)                                                       \
  {                                                                       \
    _Pragma("unroll") for (int u = 0; u < FC; ++u) {                      \
      const float* p = Wg + (size_t)(u * 64 + sr) * K + (kq) + c8;        \
      brg[s][u][0] = *(const f32x4*)p;                                    \
      brg[s][u][1] = *(const f32x4*)(p + 4);                              \
    }                                                                     \
  }
#define BWR(buf, s)                                                       \
  {                                                                       \
    _Pragma("unroll") for (int u = 0; u < FC; ++u)                        \
        *(bf16x8*)(&Bs[buf][0] + u * 4096 + ldsoff) =                     \
            cvt8(brg[s][u][0], brg[s][u][1]);                             \
  }

  // ---- prologue: As[0]=T0.A, As[1]=T1.A, Bs[0]=T0.B; T1.B in flight (set 1)
  AISS(0);
  AWR(0);
  AISS(64);
  AWR(1);
  BISS(0, 0);
  BWR(0, 0);
  if (NT > 1) BISS(64, 1);
  asm volatile("s_waitcnt lgkmcnt(0)" ::: "memory");
  __builtin_amdgcn_s_barrier();

  for (int t = 0; t < NT; ++t) {
    const int cur = t & 1;
    const bf16_t* Acur = As[cur];
    const bf16_t* Bcur = Bs[cur];
    const int k2 = (t + 2) << 6;
    bf16x8 afr[4][2];

    // ---- p1: issue 2-ahead loads, then ds_read afr + b1
    if (t + 2 < NT) {
      AISS(k2);
      BISS(k2, t & 1);
    }
    __builtin_amdgcn_sched_barrier(0);  // keep issue point here
#pragma unroll
    for (int fr = 0; fr < 4; ++fr) {
      const bf16_t* rp = Acur + (wm * 64 + fr * 16 + q16) * 64;
      afr[fr][0] = *(const bf16x8*)(rp + ((gq ^ sw) << 3));
      afr[fr][1] = *(const bf16x8*)(rp + (((4 + gq) ^ sw) << 3));
    }
    bf16x8 b1[2];
    {
      const bf16_t* rp = Bcur + (wn * 32 + q16) * 64;
      b1[0] = *(const bf16x8*)(rp + ((gq ^ sw) << 3));
      b1[1] = *(const bf16x8*)(rp + (((4 + gq) ^ sw) << 3));
    }
    asm volatile("s_waitcnt lgkmcnt(0)" ::: "memory");  // reads sampled
    __builtin_amdgcn_s_barrier();  // barA

    // ---- p1b: MFMA1 then stage to LDS (compiler waits the staging regs)
    __builtin_amdgcn_s_setprio(1);
#pragma unroll
    for (int fr = 0; fr < 4; ++fr)
#pragma unroll
      for (int kk = 0; kk < 2; ++kk)
        acc[fr][0] = __builtin_amdgcn_mfma_f32_16x16x32_bf16(
            afr[fr][kk], b1[kk], acc[fr][0], 0, 0, 0);
    __builtin_amdgcn_s_setprio(0);
    __builtin_amdgcn_sched_barrier(0);  // MFMA1 stays ahead of staging
    if (t + 1 < NT) BWR(cur ^ 1, (t + 1) & 1);
    if (t + 2 < NT) AWR(cur);

    // ---- p2: ds_read b2, MFMA2, publish
    bf16x8 b2[2];
    {
      const bf16_t* rp = Bcur + (wn * 32 + 16 + q16) * 64;
      b2[0] = *(const bf16x8*)(rp + ((gq ^ sw) << 3));
      b2[1] = *(const bf16x8*)(rp + (((4 + gq) ^ sw) << 3));
    }
    __builtin_amdgcn_s_setprio(1);
#pragma unroll
    for (int fr = 0; fr < 4; ++fr)
#pragma unroll
      for (int kk = 0; kk < 2; ++kk)
        acc[fr][1] = __builtin_amdgcn_mfma_f32_16x16x32_bf16(
            afr[fr][kk], b2[kk], acc[fr][1], 0, 0, 0);
    __builtin_amdgcn_s_setprio(0);
    asm volatile("s_waitcnt lgkmcnt(0)" ::: "memory");
    __builtin_amdgcn_s_barrier();  // barC
  }

#pragma unroll
  for (int fr = 0; fr < 4; ++fr)
#pragma unroll
    for (int fc = 0; fc < FC; ++fc)
#pragma unroll
      for (int i = 0; i < 4; ++i) {
        int row = tm + wm * 64 + fr * 16 + gq * 4 + i;
        int col = tn + wn * 32 + fc * 16 + q16;
        C[(size_t)row * N + col] = (CT)acc[fr][fc][i];
      }
#undef AISS
#undef AWR
#undef BISS
#undef BWR
}

// ---------------------------------------------------------------------------
// RMSNorm + RoPE + scatter (unchanged, validated).
// ---------------------------------------------------------------------------
__global__ __launch_bounds__(256) void rope_scatter(
    const bf16_t* __restrict__ qkv, const float* __restrict__ cosb,
    const float* __restrict__ sinb, const float* __restrict__ wq,
    const float* __restrict__ wk, bf16_t* __restrict__ qb,
    bf16_t* __restrict__ kb, bf16_t* __restrict__ vt) {
  const int row = blockIdx.x;  // b*1024 + s
  const int b = row >> 10, s = row & 1023;
  const int wave = threadIdx.x >> 6, lane = threadIdx.x & 63;
  const int d0 = 2 * lane;
  const float c0 = cosb[(size_t)row * 128 + d0];
  const float c1 = cosb[(size_t)row * 128 + d0 + 1];
  const float s0 = sinb[(size_t)row * 128 + d0];
  const float s1 = sinb[(size_t)row * 128 + d0 + 1];
  const float g0q = wq[d0], g1q = wq[d0 + 1];
  const float g0k = wk[d0], g1k = wk[d0 + 1];
  const float sign = (lane < 32) ? -1.f : 1.f;

  for (int h = wave; h < 32; h += 4) {
    const bf16_t* x = qkv + (size_t)row * 6144 + h * 128 + d0;
    float x0 = (float)x[0], x1 = (float)x[1];
    float ss = x0 * x0 + x1 * x1;
#pragma unroll
    for (int off = 1; off < 64; off <<= 1) ss += __shfl_xor(ss, off);
    float r = rsqrtf(ss * (1.0f / 128.0f) + 1e-6f);
    float n0 = x0 * r * g0q, n1 = x1 * r * g1q;
    float o0 = __shfl_xor(n0, 32), o1 = __shfl_xor(n1, 32);
    float y0 = n0 * c0 + sign * o0 * s0;
    float y1 = n1 * c1 + sign * o1 * s1;
    bf16_t* dst = qb + ((size_t)(b * 32 + h) * 1024 + s) * 128 + d0;
    dst[0] = (__bf16)y0;
    dst[1] = (__bf16)y1;
  }
  for (int h = wave; h < 8; h += 4) {
    const bf16_t* x = qkv + (size_t)row * 6144 + 4096 + h * 128 + d0;
    float x0 = (float)x[0], x1 = (float)x[1];
    float ss = x0 * x0 + x1 * x1;
#pragma unroll
    for (int off = 1; off < 64; off <<= 1) ss += __shfl_xor(ss, off);
    float r = rsqrtf(ss * (1.0f / 128.0f) + 1e-6f);
    float n0 = x0 * r * g0k, n1 = x1 * r * g1k;
    float o0 = __shfl_xor(n0, 32), o1 = __shfl_xor(n1, 32);
    float y0 = n0 * c0 + sign * o0 * s0;
    float y1 = n1 * c1 + sign * o1 * s1;
    bf16_t* dst = kb + ((size_t)(b * 8 + h) * 1024 + s) * 128 + d0;
    dst[0] = (__bf16)y0;
    dst[1] = (__bf16)y1;
  }
  for (int h = wave; h < 8; h += 4) {
    const bf16_t* x = qkv + (size_t)row * 6144 + 5120 + h * 128 + d0;
    bf16_t* dst = vt + ((size_t)(b * 8 + h) * 128 + d0) * 1024 + s;
    dst[0] = x[0];
    dst[1024] = x[1];
  }
}

// ---------------------------------------------------------------------------
// Flash attention (unchanged, validated round 3).
// ---------------------------------------------------------------------------
__global__ __launch_bounds__(256, 2) void attn_fwd(
    const bf16_t* __restrict__ Qb, const bf16_t* __restrict__ Kb,
    const bf16_t* __restrict__ Vt, bf16_t* __restrict__ Ob) {
  __shared__ __align__(16) bf16_t Kl[2][64 * 128];
  __shared__ __align__(16) bf16_t Vl[2][128 * 64];
  __shared__ __align__(16) bf16_t Pl[4][32 * 64];
  const int tid = threadIdx.x, wave = tid >> 6, lane = tid & 63;
  const int q16 = lane & 15, g = lane >> 4;
  const int bid = blockIdx.x;
  const int bh = bid >> 3, qt = bid & 7;
  const int b = bh >> 5, h = bh & 31;
  const int kvh = (b << 3) + (h >> 2);
  const bf16_t* qp = Qb + ((size_t)bh * 1024 + qt * 128 + wave * 32) * 128;
  const bf16_t* kp = Kb + (size_t)kvh * (1024 * 128);
  const bf16_t* vp = Vt + (size_t)kvh * (128 * 1024);
  const float SCALE = 0.088388347648318447f;
  const int sw = q16 & 7;

  bf16x8 qf[2][4];
#pragma unroll
  for (int m = 0; m < 2; ++m)
#pragma unroll
    for (int kc = 0; kc < 4; ++kc)
      qf[m][kc] = *(const bf16x8*)(qp + (m * 16 + q16) * 128 + kc * 32 + g * 8);

  f32x4 oacc[2][8];
#pragma unroll
  for (int m = 0; m < 2; ++m)
#pragma unroll
    for (int dc = 0; dc < 8; ++dc) oacc[m][dc] = f32x4{0.f, 0.f, 0.f, 0.f};
  float m_run[2] = {-3.0e38f, -3.0e38f}, l_run[2] = {0.f, 0.f};

#define STAGE_KV(buf, jj)                                                      \
  {                                                                            \
    _Pragma("unroll") for (int i = 0; i < 4; ++i) {                            \
      int n = (wave * 4 + i) * 64 + lane;                                      \
      int rk = n >> 4, ck = (n & 15) ^ (rk & 7);                               \
      gld_lds16(kp + (size_t)((jj) + rk) * 128 + ck * 8,                       \
                &Kl[buf][0] + (wave * 4 + i) * 512);                           \
      int rv = n >> 3, cv = (n & 7) ^ (rv & 7);                                \
      gld_lds16(vp + (size_t)rv * 1024 + (jj) + cv * 8,                        \
                &Vl[buf][0] + (wave * 4 + i) * 512);                           \
    }                                                                          \
  }

  STAGE_KV(0, 0);
  __syncthreads();
  int cur = 0;

  for (int jt = 0; jt < 16; ++jt) {
    if (jt < 15) STAGE_KV(cur ^ 1, (jt + 1) * 64);

    const bf16_t* Kc = &Kl[cur][0];
    const bf16_t* Vc = &Vl[cur][0];
    bf16_t* Plw = &Pl[wave][0];

    f32x4 st[2][4];
#pragma unroll
    for (int m = 0; m < 2; ++m)
#pragma unroll
      for (int t = 0; t < 4; ++t) st[m][t] = f32x4{0.f, 0.f, 0.f, 0.f};
#pragma unroll
    for (int t = 0; t < 4; ++t) {
      bf16x8 kf[4];
#pragma unroll
      for (int kc = 0; kc < 4; ++kc)
        kf[kc] = *(const bf16x8*)(Kc + (t * 16 + q16) * 128 + (((kc * 4 + g) ^ sw) << 3));
#pragma unroll
      for (int m = 0; m < 2; ++m)
#pragma unroll
        for (int kc = 0; kc < 4; ++kc)
          st[m][t] = __builtin_amdgcn_mfma_f32_16x16x32_bf16(kf[kc], qf[m][kc], st[m][t], 0, 0, 0);
    }

#pragma unroll
    for (int m = 0; m < 2; ++m) {
      float mx = m_run[m];
#pragma unroll
      for (int t = 0; t < 4; ++t)
#pragma unroll
        for (int i = 0; i < 4; ++i) {
          float s = st[m][t][i] * SCALE;
          st[m][t][i] = s;
          mx = fmaxf(mx, s);
        }
      mx = fmaxf(mx, __shfl_xor(mx, 16));
      mx = fmaxf(mx, __shfl_xor(mx, 32));
      float alpha = __expf(m_run[m] - mx);
      float lsum = 0.f;
      const int prow = m * 16 + q16;
#pragma unroll
      for (int t = 0; t < 4; ++t) {
        float p0 = __expf(st[m][t][0] - mx);
        float p1 = __expf(st[m][t][1] - mx);
        float p2 = __expf(st[m][t][2] - mx);
        float p3 = __expf(st[m][t][3] - mx);
        lsum += (p0 + p1) + (p2 + p3);
        int k0 = t * 16 + g * 4;
        int a0 = prow * 64 + ((((k0 >> 3)) ^ sw) << 3) + (k0 & 7);
        *(bf16x2*)(Plw + a0) = bf16x2{(__bf16)p0, (__bf16)p1};
        *(bf16x2*)(Plw + a0 + 2) = bf16x2{(__bf16)p2, (__bf16)p3};
      }
      lsum += __shfl_xor(lsum, 16);
      lsum += __shfl_xor(lsum, 32);
      l_run[m] = l_run[m] * alpha + lsum;
      m_run[m] = mx;
      float ar[4];
#pragma unroll
      for (int i = 0; i < 4; ++i) ar[i] = __shfl(alpha, g * 4 + i);
#pragma unroll
      for (int dc = 0; dc < 8; ++dc)
#pragma unroll
        for (int i = 0; i < 4; ++i) oacc[m][dc][i] *= ar[i];
    }

#pragma unroll
    for (int ks = 0; ks < 2; ++ks) {
      bf16x8 pf0 = *(const bf16x8*)(Plw + (q16)*64 + (((ks * 4 + g) ^ sw) << 3));
      bf16x8 pf1 = *(const bf16x8*)(Plw + (16 + q16) * 64 + (((ks * 4 + g) ^ sw) << 3));
#pragma unroll
      for (int dc = 0; dc < 8; ++dc) {
        bf16x8 vf = *(const bf16x8*)(Vc + (dc * 16 + q16) * 64 + (((ks * 4 + g) ^ sw) << 3));
        oacc[0][dc] = __builtin_amdgcn_mfma_f32_16x16x32_bf16(pf0, vf, oacc[0][dc], 0, 0, 0);
        oacc[1][dc] = __builtin_amdgcn_mfma_f32_16x16x32_bf16(pf1, vf, oacc[1][dc], 0, 0, 0);
      }
    }

    __syncthreads();
    cur ^= 1;
  }

  const int rowbase = (b << 10) + qt * 128 + wave * 32;
#pragma unroll
  for (int m = 0; m < 2; ++m) {
    float lr[4];
#pragma unroll
    for (int i = 0; i < 4; ++i) lr[i] = __shfl(l_run[m], g * 4 + i);
#pragma unroll
    for (int dc = 0; dc < 8; ++dc)
#pragma unroll
      for (int i = 0; i < 4; ++i) {
        int row = rowbase + m * 16 + g * 4 + i;
        int col = (h << 7) + dc * 16 + q16;
        Ob[(size_t)row * 4096 + col] = (__bf16)(oacc[m][dc][i] / lr[i]);
      }
  }
#undef STAGE_KV
}

// ---------------------------------------------------------------------------
extern "C" void kernel_launch(void* const* d_in, const int* in_sizes, int n_in,
                              void* d_out, int out_size, void* d_ws,
                              size_t ws_size, hipStream_t stream) {
  const float* hidden = (const float*)d_in[0];  // [2,1024,4096] f32
  const float* cosb = (const float*)d_in[1];    // [2,1024,128] f32
  const float* sinb = (const float*)d_in[2];    // [2,1024,128] f32
  // d_in[3]: attention_mask, all-true -> ignored
  const float* w_qkv = (const float*)d_in[4];   // [6144,4096] f32
  const float* w_qn = (const float*)d_in[5];    // [128] f32
  const float* w_kn = (const float*)d_in[6];    // [128] f32
  const float* w_o = (const float*)d_in[7];     // [4096,4096] f32
  float* out = (float*)d_out;                   // [2,1024,4096] f32

  char* ws = (char*)d_ws;
  // region0 (50.3 MB): wqkvb; after QKV GEMM reused as qb+kb+vt
  bf16_t* wqkvb = (bf16_t*)ws;
  bf16_t* qb = (bf16_t*)ws;                      // 16.8 MB
  bf16_t* kb = (bf16_t*)(ws + 16777216);         // 4.2 MB
  bf16_t* vt = (bf16_t*)(ws + 20971520);         // 4.2 MB
  // region1 (16.8 MB): hb; after QKV GEMM reused as attno
  bf16_t* hb = (bf16_t*)(ws + 50331648);
  bf16_t* attno = hb;
  // region2 (25.2 MB): qkv   -> total 92.3 MB
  bf16_t* qkv = (bf16_t*)(ws + 67108864);

  cvt_f32_bf16<<<dim3(4096), dim3(256), 0, stream>>>(hidden, hb, 8388608);
  cvt_f32_bf16<<<dim3(12288), dim3(256), 0, stream>>>(w_qkv, wqkvb, 25165824);
  gemm128<3, 4, bf16_t><<<dim3(512), dim3(512), 0, stream>>>(hb, wqkvb, qkv, 2048, 6144, 4096);
  rope_scatter<<<dim3(2048), dim3(256), 0, stream>>>(qkv, cosb, sinb, w_qn, w_kn, qb, kb, vt);
  attn_fwd<<<dim3(64 * 8), dim3(256), 0, stream>>>(qb, kb, vt, attno);
  gemmf2<float><<<dim3(512), dim3(512), 0, stream>>>(attno, w_o, out, 2048, 4096, 4096);
}

// Round 12
// 303.501 us; speedup vs baseline: 1.0932x; 1.0932x over previous
//
#include <hip/hip_runtime.h>
#include <hip/hip_bf16.h>

typedef __bf16 bf16_t;
typedef bf16_t bf16x2 __attribute__((ext_vector_type(2)));
typedef bf16_t bf16x8 __attribute__((ext_vector_type(8)));
typedef float f32x4 __attribute__((ext_vector_type(4)));

#define DEVI __device__ __forceinline__

DEVI void gld_lds16(const void* g, void* l) {
  __builtin_amdgcn_global_load_lds(
      (const __attribute__((address_space(1))) void*)g,
      (__attribute__((address_space(3))) void*)l, 16, 0, 0);
}

// ---------------------------------------------------------------------------
// f32 -> bf16 conversion, 8 elements/thread.
// ---------------------------------------------------------------------------
__global__ __launch_bounds__(256) void cvt_f32_bf16(
    const float* __restrict__ in, bf16_t* __restrict__ out, long n) {
  long i = ((long)blockIdx.x * 256 + threadIdx.x) * 8;
  if (i >= n) return;
  float4 a = *(const float4*)(in + i);
  float4 b = *(const float4*)(in + i + 4);
  bf16x8 v = {(__bf16)a.x, (__bf16)a.y, (__bf16)a.z, (__bf16)a.w,
              (__bf16)b.x, (__bf16)b.y, (__bf16)b.z, (__bf16)b.w};
  *(bf16x8*)(out + i) = v;
}

// ---------------------------------------------------------------------------
// Round-6-validated 128 x (64*FC) all-bf16 GEMM (92 us QKV @ FC=3, grid 512;
// ~72 us out-proj @ FC=2, grid 512).  8 waves (2M x 4N), BK=64, LDS
// double-buffered, XOR swizzle (16B slot ^ row&7) via pre-swizzled global
// source + linear LDS dest (global_load_lds).  Ledger: prologue
// T0.A+T0.B+T1.A vmcnt(2); t.p1 stage T+1.B (other buf); t.p2 stage T+2.A
// (cur buf); gate vmcnt(2) at p2, tail vmcnt(0).  XCD supertiling 2x4.
// Requires grid==nM*nN, nM%2==0, nN%4==0, K%64==0, K>=192.
// ---------------------------------------------------------------------------
template <int FC, int MINW, typename CT>
__global__ __launch_bounds__(512, MINW) void gemm128(
    const bf16_t* __restrict__ A, const bf16_t* __restrict__ W,
    CT* __restrict__ C, int M, int N, int K) {
  constexpr int BN = FC * 64;
  constexpr int P1 = FC / 2, P2 = FC - P1;
  __shared__ __align__(16) bf16_t As[2][128 * 64];
  __shared__ __align__(16) bf16_t Bs[2][BN * 64];
  const int tid = threadIdx.x, wave = tid >> 6, lane = tid & 63;
  const int q16 = lane & 15, gq = lane >> 4, sw = q16 & 7;
  const int wm = wave >> 2, wn = wave & 3;
  const int nM = M >> 7, nN = N / BN;
  const int cM = nM >> 1, cN = nN >> 2;
  const int xcd = (int)blockIdx.x & 7, wi = (int)blockIdx.x >> 3;
  const int tm = ((xcd >> 2) * cM + wi / cN) << 7;
  const int tn = ((xcd & 3) * cN + wi % cN) * BN;
  const int NT = K >> 6;
  const bf16_t* Ag = A + (size_t)tm * K;
  const bf16_t* Wg = W + (size_t)tn * K;
  const int sr = (wave << 3) + (lane >> 3);
  const int scol = (((lane & 7) ^ (sr & 7)) << 3);

#define STG(gbase, kq, uu, ldsbuf)                              \
  gld_lds16((gbase) + (size_t)((uu)*64 + sr) * K + (kq) + scol, \
            &(ldsbuf)[0] + (uu)*4096 + (wave << 9))

  f32x4 acc[4][FC];
#pragma unroll
  for (int i = 0; i < 4; ++i)
#pragma unroll
    for (int j = 0; j < FC; ++j) acc[i][j] = f32x4{0.f, 0.f, 0.f, 0.f};

  STG(Ag, 0, 0, As[0]);
  STG(Ag, 0, 1, As[0]);
#pragma unroll
  for (int u = 0; u < FC; ++u) STG(Wg, 0, u, Bs[0]);
  STG(Ag, 64, 0, As[1]);
  STG(Ag, 64, 1, As[1]);
  asm volatile("s_waitcnt vmcnt(2)" ::: "memory");
  __builtin_amdgcn_s_barrier();

  for (int t = 0; t < NT; ++t) {
    const int cur = t & 1;
    const bf16_t* Acur = As[cur];
    const bf16_t* Bcur = Bs[cur];
    const int k1 = (t + 1) << 6, k2 = (t + 2) << 6;
    bf16x8 afr[4][2];

#pragma unroll
    for (int fr = 0; fr < 4; ++fr) {
      const bf16_t* rp = Acur + (wm * 64 + fr * 16 + q16) * 64;
      afr[fr][0] = *(const bf16x8*)(rp + ((gq ^ sw) << 3));
      afr[fr][1] = *(const bf16x8*)(rp + (((4 + gq) ^ sw) << 3));
    }
    bf16x8 b1[P1][2];
#pragma unroll
    for (int fc = 0; fc < P1; ++fc) {
      const bf16_t* rp = Bcur + (wn * (16 * FC) + fc * 16 + q16) * 64;
      b1[fc][0] = *(const bf16x8*)(rp + ((gq ^ sw) << 3));
      b1[fc][1] = *(const bf16x8*)(rp + (((4 + gq) ^ sw) << 3));
    }
    if (t + 1 < NT) {
#pragma unroll
      for (int u = 0; u < FC; ++u) STG(Wg, k1, u, Bs[cur ^ 1]);
    }
    __builtin_amdgcn_s_barrier();
    __builtin_amdgcn_s_setprio(1);
#pragma unroll
    for (int fr = 0; fr < 4; ++fr)
#pragma unroll
      for (int fc = 0; fc < P1; ++fc)
#pragma unroll
        for (int kk = 0; kk < 2; ++kk)
          acc[fr][fc] = __builtin_amdgcn_mfma_f32_16x16x32_bf16(
              afr[fr][kk], b1[fc][kk], acc[fr][fc], 0, 0, 0);
    __builtin_amdgcn_s_setprio(0);
    asm volatile("" ::: "memory");
    __builtin_amdgcn_s_barrier();

    bf16x8 b2[P2][2];
#pragma unroll
    for (int f2 = 0; f2 < P2; ++f2) {
      const bf16_t* rp = Bcur + (wn * (16 * FC) + (P1 + f2) * 16 + q16) * 64;
      b2[f2][0] = *(const bf16x8*)(rp + ((gq ^ sw) << 3));
      b2[f2][1] = *(const bf16x8*)(rp + (((4 + gq) ^ sw) << 3));
    }
    if (t + 2 < NT) {
      STG(Ag, k2, 0, As[cur]);
      STG(Ag, k2, 1, As[cur]);
    }
    __builtin_amdgcn_s_barrier();
    __builtin_amdgcn_s_setprio(1);
#pragma unroll
    for (int fr = 0; fr < 4; ++fr)
#pragma unroll
      for (int f2 = 0; f2 < P2; ++f2)
#pragma unroll
        for (int kk = 0; kk < 2; ++kk)
          acc[fr][P1 + f2] = __builtin_amdgcn_mfma_f32_16x16x32_bf16(
              afr[fr][kk], b2[f2][kk], acc[fr][P1 + f2], 0, 0, 0);
    __builtin_amdgcn_s_setprio(0);
    if (t + 2 < NT)
      asm volatile("s_waitcnt vmcnt(2)" ::: "memory");
    else
      asm volatile("s_waitcnt vmcnt(0)" ::: "memory");
    __builtin_amdgcn_s_barrier();
  }

#pragma unroll
  for (int fr = 0; fr < 4; ++fr)
#pragma unroll
    for (int fc = 0; fc < FC; ++fc)
#pragma unroll
      for (int i = 0; i < 4; ++i) {
        int row = tm + wm * 64 + fr * 16 + gq * 4 + i;
        int col = tn + wn * (16 * FC) + fc * 16 + q16;
        C[(size_t)row * N + col] = (CT)acc[fr][fc][i];
      }
#undef STG
}

// ---------------------------------------------------------------------------
// RMSNorm + RoPE + scatter (unchanged, validated).
// ---------------------------------------------------------------------------
__global__ __launch_bounds__(256) void rope_scatter(
    const bf16_t* __restrict__ qkv, const float* __restrict__ cosb,
    const float* __restrict__ sinb, const float* __restrict__ wq,
    const float* __restrict__ wk, bf16_t* __restrict__ qb,
    bf16_t* __restrict__ kb, bf16_t* __restrict__ vt) {
  const int row = blockIdx.x;  // b*1024 + s
  const int b = row >> 10, s = row & 1023;
  const int wave = threadIdx.x >> 6, lane = threadIdx.x & 63;
  const int d0 = 2 * lane;
  const float c0 = cosb[(size_t)row * 128 + d0];
  const float c1 = cosb[(size_t)row * 128 + d0 + 1];
  const float s0 = sinb[(size_t)row * 128 + d0];
  const float s1 = sinb[(size_t)row * 128 + d0 + 1];
  const float g0q = wq[d0], g1q = wq[d0 + 1];
  const float g0k = wk[d0], g1k = wk[d0 + 1];
  const float sign = (lane < 32) ? -1.f : 1.f;

  for (int h = wave; h < 32; h += 4) {
    const bf16_t* x = qkv + (size_t)row * 6144 + h * 128 + d0;
    float x0 = (float)x[0], x1 = (float)x[1];
    float ss = x0 * x0 + x1 * x1;
#pragma unroll
    for (int off = 1; off < 64; off <<= 1) ss += __shfl_xor(ss, off);
    float r = rsqrtf(ss * (1.0f / 128.0f) + 1e-6f);
    float n0 = x0 * r * g0q, n1 = x1 * r * g1q;
    float o0 = __shfl_xor(n0, 32), o1 = __shfl_xor(n1, 32);
    float y0 = n0 * c0 + sign * o0 * s0;
    float y1 = n1 * c1 + sign * o1 * s1;
    bf16_t* dst = qb + ((size_t)(b * 32 + h) * 1024 + s) * 128 + d0;
    dst[0] = (__bf16)y0;
    dst[1] = (__bf16)y1;
  }
  for (int h = wave; h < 8; h += 4) {
    const bf16_t* x = qkv + (size_t)row * 6144 + 4096 + h * 128 + d0;
    float x0 = (float)x[0], x1 = (float)x[1];
    float ss = x0 * x0 + x1 * x1;
#pragma unroll
    for (int off = 1; off < 64; off <<= 1) ss += __shfl_xor(ss, off);
    float r = rsqrtf(ss * (1.0f / 128.0f) + 1e-6f);
    float n0 = x0 * r * g0k, n1 = x1 * r * g1k;
    float o0 = __shfl_xor(n0, 32), o1 = __shfl_xor(n1, 32);
    float y0 = n0 * c0 + sign * o0 * s0;
    float y1 = n1 * c1 + sign * o1 * s1;
    bf16_t* dst = kb + ((size_t)(b * 8 + h) * 1024 + s) * 128 + d0;
    dst[0] = (__bf16)y0;
    dst[1] = (__bf16)y1;
  }
  for (int h = wave; h < 8; h += 4) {
    const bf16_t* x = qkv + (size_t)row * 6144 + 5120 + h * 128 + d0;
    bf16_t* dst = vt + ((size_t)(b * 8 + h) * 128 + d0) * 1024 + s;
    dst[0] = x[0];
    dst[1024] = x[1];
  }
}

// ---------------------------------------------------------------------------
// Flash attention v3: K staged in LDS (double-buffered, swizzled, validated
// structure), V read DIRECTLY from global (L2-resident: 256KB/kvh shared by
// 32 blocks; validated index pattern from round 2).  LDS 72->48KB =>
// 3 blocks/CU (12 waves/CU, +50% latency hiding).
// ---------------------------------------------------------------------------
__global__ __launch_bounds__(256, 2) void attn_fwd(
    const bf16_t* __restrict__ Qb, const bf16_t* __restrict__ Kb,
    const bf16_t* __restrict__ Vt, bf16_t* __restrict__ Ob) {
  __shared__ __align__(16) bf16_t Kl[2][64 * 128];  // 32KB dbuf, swizzled
  __shared__ __align__(16) bf16_t Pl[4][32 * 64];   // 16KB, per-wave swizzled
  const int tid = threadIdx.x, wave = tid >> 6, lane = tid & 63;
  const int q16 = lane & 15, g = lane >> 4;
  const int bid = blockIdx.x;
  const int bh = bid >> 3, qt = bid & 7;
  const int b = bh >> 5, h = bh & 31;
  const int kvh = (b << 3) + (h >> 2);
  const bf16_t* qp = Qb + ((size_t)bh * 1024 + qt * 128 + wave * 32) * 128;
  const bf16_t* kp = Kb + (size_t)kvh * (1024 * 128);
  const bf16_t* vp = Vt + (size_t)kvh * (128 * 1024);
  const float SCALE = 0.088388347648318447f;
  const int sw = q16 & 7;

  bf16x8 qf[2][4];
#pragma unroll
  for (int m = 0; m < 2; ++m)
#pragma unroll
    for (int kc = 0; kc < 4; ++kc)
      qf[m][kc] = *(const bf16x8*)(qp + (m * 16 + q16) * 128 + kc * 32 + g * 8);

  f32x4 oacc[2][8];
#pragma unroll
  for (int m = 0; m < 2; ++m)
#pragma unroll
    for (int dc = 0; dc < 8; ++dc) oacc[m][dc] = f32x4{0.f, 0.f, 0.f, 0.f};
  float m_run[2] = {-3.0e38f, -3.0e38f}, l_run[2] = {0.f, 0.f};

  // K tile 64x128 = 16 row-chunks of 8 rows; 4 gld_lds16 per wave.
#define STAGE_K(buf, jj)                                  \
  {                                                       \
    _Pragma("unroll") for (int i = 0; i < 4; ++i) {       \
      int n = (wave * 4 + i) * 64 + lane;                 \
      int rk = n >> 4, ck = (n & 15) ^ (rk & 7);          \
      gld_lds16(kp + (size_t)((jj) + rk) * 128 + ck * 8,  \
                &Kl[buf][0] + (wave * 4 + i) * 512);      \
    }                                                     \
  }

  STAGE_K(0, 0);
  __syncthreads();
  int cur = 0;

  for (int jt = 0; jt < 16; ++jt) {
    const int j = jt * 64;
    if (jt < 15) STAGE_K(cur ^ 1, j + 64);

    const bf16_t* Kc = &Kl[cur][0];
    bf16_t* Plw = &Pl[wave][0];

    f32x4 st[2][4];
#pragma unroll
    for (int m = 0; m < 2; ++m)
#pragma unroll
      for (int t = 0; t < 4; ++t) st[m][t] = f32x4{0.f, 0.f, 0.f, 0.f};
#pragma unroll
    for (int t = 0; t < 4; ++t) {
      bf16x8 kf[4];
#pragma unroll
      for (int kc = 0; kc < 4; ++kc)
        kf[kc] = *(const bf16x8*)(Kc + (t * 16 + q16) * 128 + (((kc * 4 + g) ^ sw) << 3));
#pragma unroll
      for (int m = 0; m < 2; ++m)
#pragma unroll
        for (int kc = 0; kc < 4; ++kc)
          st[m][t] = __builtin_amdgcn_mfma_f32_16x16x32_bf16(kf[kc], qf[m][kc], st[m][t], 0, 0, 0);
    }

#pragma unroll
    for (int m = 0; m < 2; ++m) {
      float mx = m_run[m];
#pragma unroll
      for (int t = 0; t < 4; ++t)
#pragma unroll
        for (int i = 0; i < 4; ++i) {
          float s = st[m][t][i] * SCALE;
          st[m][t][i] = s;
          mx = fmaxf(mx, s);
        }
      mx = fmaxf(mx, __shfl_xor(mx, 16));
      mx = fmaxf(mx, __shfl_xor(mx, 32));
      float alpha = __expf(m_run[m] - mx);
      float lsum = 0.f;
      const int prow = m * 16 + q16;
#pragma unroll
      for (int t = 0; t < 4; ++t) {
        float p0 = __expf(st[m][t][0] - mx);
        float p1 = __expf(st[m][t][1] - mx);
        float p2 = __expf(st[m][t][2] - mx);
        float p3 = __expf(st[m][t][3] - mx);
        lsum += (p0 + p1) + (p2 + p3);
        int k0 = t * 16 + g * 4;
        int a0 = prow * 64 + ((((k0 >> 3)) ^ sw) << 3) + (k0 & 7);
        *(bf16x2*)(Plw + a0) = bf16x2{(__bf16)p0, (__bf16)p1};
        *(bf16x2*)(Plw + a0 + 2) = bf16x2{(__bf16)p2, (__bf16)p3};
      }
      lsum += __shfl_xor(lsum, 16);
      lsum += __shfl_xor(lsum, 32);
      l_run[m] = l_run[m] * alpha + lsum;
      m_run[m] = mx;
      float ar[4];
#pragma unroll
      for (int i = 0; i < 4; ++i) ar[i] = __shfl(alpha, g * 4 + i);
#pragma unroll
      for (int dc = 0; dc < 8; ++dc)
#pragma unroll
        for (int i = 0; i < 4; ++i) oacc[m][dc][i] *= ar[i];
    }

    // PV: P from per-wave LDS; V fragments straight from global (L2-hit).
#pragma unroll
    for (int ks = 0; ks < 2; ++ks) {
      bf16x8 pf0 = *(const bf16x8*)(Plw + (q16)*64 + (((ks * 4 + g) ^ sw) << 3));
      bf16x8 pf1 = *(const bf16x8*)(Plw + (16 + q16) * 64 + (((ks * 4 + g) ^ sw) << 3));
#pragma unroll
      for (int dc = 0; dc < 8; ++dc) {
        bf16x8 vf = *(const bf16x8*)(vp + (size_t)(dc * 16 + q16) * 1024 + j + (ks * 4 + g) * 8);
        oacc[0][dc] = __builtin_amdgcn_mfma_f32_16x16x32_bf16(pf0, vf, oacc[0][dc], 0, 0, 0);
        oacc[1][dc] = __builtin_amdgcn_mfma_f32_16x16x32_bf16(pf1, vf, oacc[1][dc], 0, 0, 0);
      }
    }

    __syncthreads();
    cur ^= 1;
  }

  const int rowbase = (b << 10) + qt * 128 + wave * 32;
#pragma unroll
  for (int m = 0; m < 2; ++m) {
    float lr[4];
#pragma unroll
    for (int i = 0; i < 4; ++i) lr[i] = __shfl(l_run[m], g * 4 + i);
#pragma unroll
    for (int dc = 0; dc < 8; ++dc)
#pragma unroll
      for (int i = 0; i < 4; ++i) {
        int row = rowbase + m * 16 + g * 4 + i;
        int col = (h << 7) + dc * 16 + q16;
        Ob[(size_t)row * 4096 + col] = (__bf16)(oacc[m][dc][i] / lr[i]);
      }
  }
#undef STAGE_K
}

// ---------------------------------------------------------------------------
extern "C" void kernel_launch(void* const* d_in, const int* in_sizes, int n_in,
                              void* d_out, int out_size, void* d_ws,
                              size_t ws_size, hipStream_t stream) {
  const float* hidden = (const float*)d_in[0];  // [2,1024,4096] f32
  const float* cosb = (const float*)d_in[1];    // [2,1024,128] f32
  const float* sinb = (const float*)d_in[2];    // [2,1024,128] f32
  // d_in[3]: attention_mask, all-true -> ignored
  const float* w_qkv = (const float*)d_in[4];   // [6144,4096] f32
  const float* w_qn = (const float*)d_in[5];    // [128] f32
  const float* w_kn = (const float*)d_in[6];    // [128] f32
  const float* w_o = (const float*)d_in[7];     // [4096,4096] f32
  float* out = (float*)d_out;                   // [2,1024,4096] f32

  char* ws = (char*)d_ws;
  // region0 (50.3 MB): wqkvb; after QKV GEMM reused as wob (33.5) + qb (16.8)
  bf16_t* wqkvb = (bf16_t*)ws;
  bf16_t* wob = (bf16_t*)ws;
  bf16_t* qb = (bf16_t*)(ws + 33554432);
  // region1 (16.8 MB): hb; after QKV GEMM reused as attno
  bf16_t* hb = (bf16_t*)(ws + 50331648);
  bf16_t* attno = hb;
  // region2 (25.2 MB): qkv
  bf16_t* qkv = (bf16_t*)(ws + 67108864);
  // region3: kb (4.2) + vt (4.2)  -> total 100.7 MB (round-2..6 footprint)
  bf16_t* kb = (bf16_t*)(ws + 92274688);
  bf16_t* vt = (bf16_t*)(ws + 96468992);

  cvt_f32_bf16<<<dim3(4096), dim3(256), 0, stream>>>(hidden, hb, 8388608);
  cvt_f32_bf16<<<dim3(12288), dim3(256), 0, stream>>>(w_qkv, wqkvb, 25165824);
  gemm128<3, 4, bf16_t><<<dim3(512), dim3(512), 0, stream>>>(hb, wqkvb, qkv, 2048, 6144, 4096);
  cvt_f32_bf16<<<dim3(8192), dim3(256), 0, stream>>>(w_o, wob, 16777216);
  rope_scatter<<<dim3(2048), dim3(256), 0, stream>>>(qkv, cosb, sinb, w_qn, w_kn, qb, kb, vt);
  attn_fwd<<<dim3(64 * 8), dim3(256), 0, stream>>>(qb, kb, vt, attno);
  gemm128<2, 4, float><<<dim3(512), dim3(512), 0, stream>>>(attno, wob, out, 2048, 4096, 4096);
}

// Round 13
// 280.171 us; speedup vs baseline: 1.1842x; 1.0833x over previous
//
#include <hip/hip_runtime.h>
#include <hip/hip_bf16.h>

typedef __bf16 bf16_t;
typedef bf16_t bf16x2 __attribute__((ext_vector_type(2)));
typedef bf16_t bf16x8 __attribute__((ext_vector_type(8)));
typedef float f32x4 __attribute__((ext_vector_type(4)));

#define DEVI __device__ __forceinline__

DEVI void gld_lds16(const void* g, void* l) {
  __builtin_amdgcn_global_load_lds(
      (const __attribute__((address_space(1))) void*)g,
      (__attribute__((address_space(3))) void*)l, 16, 0, 0);
}

// ---------------------------------------------------------------------------
// f32 -> bf16 conversion, 8 elements/thread.
// ---------------------------------------------------------------------------
__global__ __launch_bounds__(256) void cvt_f32_bf16(
    const float* __restrict__ in, bf16_t* __restrict__ out, long n) {
  long i = ((long)blockIdx.x * 256 + threadIdx.x) * 8;
  if (i >= n) return;
  float4 a = *(const float4*)(in + i);
  float4 b = *(const float4*)(in + i + 4);
  bf16x8 v = {(__bf16)a.x, (__bf16)a.y, (__bf16)a.z, (__bf16)a.w,
              (__bf16)b.x, (__bf16)b.y, (__bf16)b.z, (__bf16)b.w};
  *(bf16x8*)(out + i) = v;
}

// Two-segment variant: converts a (na elems) then b (nb elems) in one launch.
// na, nb must be multiples of 2048 (block covers 2048 elems).
__global__ __launch_bounds__(256) void cvt_f32_bf16_2(
    const float* __restrict__ ina, bf16_t* __restrict__ outa, long na,
    const float* __restrict__ inb, bf16_t* __restrict__ outb, long nb) {
  long i = ((long)blockIdx.x * 256 + threadIdx.x) * 8;
  const float* src;
  bf16_t* dst;
  if (i < na) {
    src = ina + i;
    dst = outa + i;
  } else {
    long j = i - na;
    if (j >= nb) return;
    src = inb + j;
    dst = outb + j;
  }
  float4 a = *(const float4*)src;
  float4 b = *(const float4*)(src + 4);
  bf16x8 v = {(__bf16)a.x, (__bf16)a.y, (__bf16)a.z, (__bf16)a.w,
              (__bf16)b.x, (__bf16)b.y, (__bf16)b.z, (__bf16)b.w};
  *(bf16x8*)dst = v;
}

// ---------------------------------------------------------------------------
// Round-6-validated 128 x (64*FC) all-bf16 GEMM (92 us QKV @ FC=3, grid 512;
// ~72 us out-proj @ FC=2, grid 512).  8 waves (2M x 4N), BK=64, LDS
// double-buffered, XOR swizzle (16B slot ^ row&7) via pre-swizzled global
// source + linear LDS dest (global_load_lds).  Ledger: prologue
// T0.A+T0.B+T1.A vmcnt(2); t.p1 stage T+1.B (other buf); t.p2 stage T+2.A
// (cur buf); gate vmcnt(2) at p2, tail vmcnt(0).  XCD supertiling 2x4.
// Requires grid==nM*nN, nM%2==0, nN%4==0, K%64==0, K>=192.
// ---------------------------------------------------------------------------
template <int FC, int MINW, typename CT>
__global__ __launch_bounds__(512, MINW) void gemm128(
    const bf16_t* __restrict__ A, const bf16_t* __restrict__ W,
    CT* __restrict__ C, int M, int N, int K) {
  constexpr int BN = FC * 64;
  constexpr int P1 = FC / 2, P2 = FC - P1;
  __shared__ __align__(16) bf16_t As[2][128 * 64];
  __shared__ __align__(16) bf16_t Bs[2][BN * 64];
  const int tid = threadIdx.x, wave = tid >> 6, lane = tid & 63;
  const int q16 = lane & 15, gq = lane >> 4, sw = q16 & 7;
  const int wm = wave >> 2, wn = wave & 3;
  const int nM = M >> 7, nN = N / BN;
  const int cM = nM >> 1, cN = nN >> 2;
  const int xcd = (int)blockIdx.x & 7, wi = (int)blockIdx.x >> 3;
  const int tm = ((xcd >> 2) * cM + wi / cN) << 7;
  const int tn = ((xcd & 3) * cN + wi % cN) * BN;
  const int NT = K >> 6;
  const bf16_t* Ag = A + (size_t)tm * K;
  const bf16_t* Wg = W + (size_t)tn * K;
  const int sr = (wave << 3) + (lane >> 3);
  const int scol = (((lane & 7) ^ (sr & 7)) << 3);

#define STG(gbase, kq, uu, ldsbuf)                              \
  gld_lds16((gbase) + (size_t)((uu)*64 + sr) * K + (kq) + scol, \
            &(ldsbuf)[0] + (uu)*4096 + (wave << 9))

  f32x4 acc[4][FC];
#pragma unroll
  for (int i = 0; i < 4; ++i)
#pragma unroll
    for (int j = 0; j < FC; ++j) acc[i][j] = f32x4{0.f, 0.f, 0.f, 0.f};

  STG(Ag, 0, 0, As[0]);
  STG(Ag, 0, 1, As[0]);
#pragma unroll
  for (int u = 0; u < FC; ++u) STG(Wg, 0, u, Bs[0]);
  STG(Ag, 64, 0, As[1]);
  STG(Ag, 64, 1, As[1]);
  asm volatile("s_waitcnt vmcnt(2)" ::: "memory");
  __builtin_amdgcn_s_barrier();

  for (int t = 0; t < NT; ++t) {
    const int cur = t & 1;
    const bf16_t* Acur = As[cur];
    const bf16_t* Bcur = Bs[cur];
    const int k1 = (t + 1) << 6, k2 = (t + 2) << 6;
    bf16x8 afr[4][2];

#pragma unroll
    for (int fr = 0; fr < 4; ++fr) {
      const bf16_t* rp = Acur + (wm * 64 + fr * 16 + q16) * 64;
      afr[fr][0] = *(const bf16x8*)(rp + ((gq ^ sw) << 3));
      afr[fr][1] = *(const bf16x8*)(rp + (((4 + gq) ^ sw) << 3));
    }
    bf16x8 b1[P1][2];
#pragma unroll
    for (int fc = 0; fc < P1; ++fc) {
      const bf16_t* rp = Bcur + (wn * (16 * FC) + fc * 16 + q16) * 64;
      b1[fc][0] = *(const bf16x8*)(rp + ((gq ^ sw) << 3));
      b1[fc][1] = *(const bf16x8*)(rp + (((4 + gq) ^ sw) << 3));
    }
    if (t + 1 < NT) {
#pragma unroll
      for (int u = 0; u < FC; ++u) STG(Wg, k1, u, Bs[cur ^ 1]);
    }
    __builtin_amdgcn_s_barrier();
    __builtin_amdgcn_s_setprio(1);
#pragma unroll
    for (int fr = 0; fr < 4; ++fr)
#pragma unroll
      for (int fc = 0; fc < P1; ++fc)
#pragma unroll
        for (int kk = 0; kk < 2; ++kk)
          acc[fr][fc] = __builtin_amdgcn_mfma_f32_16x16x32_bf16(
              afr[fr][kk], b1[fc][kk], acc[fr][fc], 0, 0, 0);
    __builtin_amdgcn_s_setprio(0);
    asm volatile("" ::: "memory");
    __builtin_amdgcn_s_barrier();

    bf16x8 b2[P2][2];
#pragma unroll
    for (int f2 = 0; f2 < P2; ++f2) {
      const bf16_t* rp = Bcur + (wn * (16 * FC) + (P1 + f2) * 16 + q16) * 64;
      b2[f2][0] = *(const bf16x8*)(rp + ((gq ^ sw) << 3));
      b2[f2][1] = *(const bf16x8*)(rp + (((4 + gq) ^ sw) << 3));
    }
    if (t + 2 < NT) {
      STG(Ag, k2, 0, As[cur]);
      STG(Ag, k2, 1, As[cur]);
    }
    __builtin_amdgcn_s_barrier();
    __builtin_amdgcn_s_setprio(1);
#pragma unroll
    for (int fr = 0; fr < 4; ++fr)
#pragma unroll
      for (int f2 = 0; f2 < P2; ++f2)
#pragma unroll
        for (int kk = 0; kk < 2; ++kk)
          acc[fr][P1 + f2] = __builtin_amdgcn_mfma_f32_16x16x32_bf16(
              afr[fr][kk], b2[f2][kk], acc[fr][P1 + f2], 0, 0, 0);
    __builtin_amdgcn_s_setprio(0);
    if (t + 2 < NT)
      asm volatile("s_waitcnt vmcnt(2)" ::: "memory");
    else
      asm volatile("s_waitcnt vmcnt(0)" ::: "memory");
    __builtin_amdgcn_s_barrier();
  }

#pragma unroll
  for (int fr = 0; fr < 4; ++fr)
#pragma unroll
    for (int fc = 0; fc < FC; ++fc)
#pragma unroll
      for (int i = 0; i < 4; ++i) {
        int row = tm + wm * 64 + fr * 16 + gq * 4 + i;
        int col = tn + wn * (16 * FC) + fc * 16 + q16;
        C[(size_t)row * N + col] = (CT)acc[fr][fc][i];
      }
#undef STG
}

// ---------------------------------------------------------------------------
// RMSNorm + RoPE + scatter (unchanged, validated).
// ---------------------------------------------------------------------------
__global__ __launch_bounds__(256) void rope_scatter(
    const bf16_t* __restrict__ qkv, const float* __restrict__ cosb,
    const float* __restrict__ sinb, const float* __restrict__ wq,
    const float* __restrict__ wk, bf16_t* __restrict__ qb,
    bf16_t* __restrict__ kb, bf16_t* __restrict__ vt) {
  const int row = blockIdx.x;  // b*1024 + s
  const int b = row >> 10, s = row & 1023;
  const int wave = threadIdx.x >> 6, lane = threadIdx.x & 63;
  const int d0 = 2 * lane;
  const float c0 = cosb[(size_t)row * 128 + d0];
  const float c1 = cosb[(size_t)row * 128 + d0 + 1];
  const float s0 = sinb[(size_t)row * 128 + d0];
  const float s1 = sinb[(size_t)row * 128 + d0 + 1];
  const float g0q = wq[d0], g1q = wq[d0 + 1];
  const float g0k = wk[d0], g1k = wk[d0 + 1];
  const float sign = (lane < 32) ? -1.f : 1.f;

  for (int h = wave; h < 32; h += 4) {
    const bf16_t* x = qkv + (size_t)row * 6144 + h * 128 + d0;
    float x0 = (float)x[0], x1 = (float)x[1];
    float ss = x0 * x0 + x1 * x1;
#pragma unroll
    for (int off = 1; off < 64; off <<= 1) ss += __shfl_xor(ss, off);
    float r = rsqrtf(ss * (1.0f / 128.0f) + 1e-6f);
    float n0 = x0 * r * g0q, n1 = x1 * r * g1q;
    float o0 = __shfl_xor(n0, 32), o1 = __shfl_xor(n1, 32);
    float y0 = n0 * c0 + sign * o0 * s0;
    float y1 = n1 * c1 + sign * o1 * s1;
    bf16_t* dst = qb + ((size_t)(b * 32 + h) * 1024 + s) * 128 + d0;
    dst[0] = (__bf16)y0;
    dst[1] = (__bf16)y1;
  }
  for (int h = wave; h < 8; h += 4) {
    const bf16_t* x = qkv + (size_t)row * 6144 + 4096 + h * 128 + d0;
    float x0 = (float)x[0], x1 = (float)x[1];
    float ss = x0 * x0 + x1 * x1;
#pragma unroll
    for (int off = 1; off < 64; off <<= 1) ss += __shfl_xor(ss, off);
    float r = rsqrtf(ss * (1.0f / 128.0f) + 1e-6f);
    float n0 = x0 * r * g0k, n1 = x1 * r * g1k;
    float o0 = __shfl_xor(n0, 32), o1 = __shfl_xor(n1, 32);
    float y0 = n0 * c0 + sign * o0 * s0;
    float y1 = n1 * c1 + sign * o1 * s1;
    bf16_t* dst = kb + ((size_t)(b * 8 + h) * 1024 + s) * 128 + d0;
    dst[0] = (__bf16)y0;
    dst[1] = (__bf16)y1;
  }
  for (int h = wave; h < 8; h += 4) {
    const bf16_t* x = qkv + (size_t)row * 6144 + 5120 + h * 128 + d0;
    bf16_t* dst = vt + ((size_t)(b * 8 + h) * 128 + d0) * 1024 + s;
    dst[0] = x[0];
    dst[1024] = x[1];
  }
}

// ---------------------------------------------------------------------------
// Flash attention (round-3-validated: K AND V staged in LDS, double-buffered,
// swizzled; per-wave swizzled P tile; one __syncthreads per 64-kv step).
// ---------------------------------------------------------------------------
__global__ __launch_bounds__(256, 2) void attn_fwd(
    const bf16_t* __restrict__ Qb, const bf16_t* __restrict__ Kb,
    const bf16_t* __restrict__ Vt, bf16_t* __restrict__ Ob) {
  __shared__ __align__(16) bf16_t Kl[2][64 * 128];
  __shared__ __align__(16) bf16_t Vl[2][128 * 64];
  __shared__ __align__(16) bf16_t Pl[4][32 * 64];
  const int tid = threadIdx.x, wave = tid >> 6, lane = tid & 63;
  const int q16 = lane & 15, g = lane >> 4;
  const int bid = blockIdx.x;
  const int bh = bid >> 3, qt = bid & 7;
  const int b = bh >> 5, h = bh & 31;
  const int kvh = (b << 3) + (h >> 2);
  const bf16_t* qp = Qb + ((size_t)bh * 1024 + qt * 128 + wave * 32) * 128;
  const bf16_t* kp = Kb + (size_t)kvh * (1024 * 128);
  const bf16_t* vp = Vt + (size_t)kvh * (128 * 1024);
  const float SCALE = 0.088388347648318447f;
  const int sw = q16 & 7;

  bf16x8 qf[2][4];
#pragma unroll
  for (int m = 0; m < 2; ++m)
#pragma unroll
    for (int kc = 0; kc < 4; ++kc)
      qf[m][kc] = *(const bf16x8*)(qp + (m * 16 + q16) * 128 + kc * 32 + g * 8);

  f32x4 oacc[2][8];
#pragma unroll
  for (int m = 0; m < 2; ++m)
#pragma unroll
    for (int dc = 0; dc < 8; ++dc) oacc[m][dc] = f32x4{0.f, 0.f, 0.f, 0.f};
  float m_run[2] = {-3.0e38f, -3.0e38f}, l_run[2] = {0.f, 0.f};

#define STAGE_KV(buf, jj)                                                      \
  {                                                                            \
    _Pragma("unroll") for (int i = 0; i < 4; ++i) {                            \
      int n = (wave * 4 + i) * 64 + lane;                                      \
      int rk = n >> 4, ck = (n & 15) ^ (rk & 7);                               \
      gld_lds16(kp + (size_t)((jj) + rk) * 128 + ck * 8,                       \
                &Kl[buf][0] + (wave * 4 + i) * 512);                           \
      int rv = n >> 3, cv = (n & 7) ^ (rv & 7);                                \
      gld_lds16(vp + (size_t)rv * 1024 + (jj) + cv * 8,                        \
                &Vl[buf][0] + (wave * 4 + i) * 512);                           \
    }                                                                          \
  }

  STAGE_KV(0, 0);
  __syncthreads();
  int cur = 0;

  for (int jt = 0; jt < 16; ++jt) {
    if (jt < 15) STAGE_KV(cur ^ 1, (jt + 1) * 64);

    const bf16_t* Kc = &Kl[cur][0];
    const bf16_t* Vc = &Vl[cur][0];
    bf16_t* Plw = &Pl[wave][0];

    f32x4 st[2][4];
#pragma unroll
    for (int m = 0; m < 2; ++m)
#pragma unroll
      for (int t = 0; t < 4; ++t) st[m][t] = f32x4{0.f, 0.f, 0.f, 0.f};
#pragma unroll
    for (int t = 0; t < 4; ++t) {
      bf16x8 kf[4];
#pragma unroll
      for (int kc = 0; kc < 4; ++kc)
        kf[kc] = *(const bf16x8*)(Kc + (t * 16 + q16) * 128 + (((kc * 4 + g) ^ sw) << 3));
#pragma unroll
      for (int m = 0; m < 2; ++m)
#pragma unroll
        for (int kc = 0; kc < 4; ++kc)
          st[m][t] = __builtin_amdgcn_mfma_f32_16x16x32_bf16(kf[kc], qf[m][kc], st[m][t], 0, 0, 0);
    }

#pragma unroll
    for (int m = 0; m < 2; ++m) {
      float mx = m_run[m];
#pragma unroll
      for (int t = 0; t < 4; ++t)
#pragma unroll
        for (int i = 0; i < 4; ++i) {
          float s = st[m][t][i] * SCALE;
          st[m][t][i] = s;
          mx = fmaxf(mx, s);
        }
      mx = fmaxf(mx, __shfl_xor(mx, 16));
      mx = fmaxf(mx, __shfl_xor(mx, 32));
      float alpha = __expf(m_run[m] - mx);
      float lsum = 0.f;
      const int prow = m * 16 + q16;
#pragma unroll
      for (int t = 0; t < 4; ++t) {
        float p0 = __expf(st[m][t][0] - mx);
        float p1 = __expf(st[m][t][1] - mx);
        float p2 = __expf(st[m][t][2] - mx);
        float p3 = __expf(st[m][t][3] - mx);
        lsum += (p0 + p1) + (p2 + p3);
        int k0 = t * 16 + g * 4;
        int a0 = prow * 64 + ((((k0 >> 3)) ^ sw) << 3) + (k0 & 7);
        *(bf16x2*)(Plw + a0) = bf16x2{(__bf16)p0, (__bf16)p1};
        *(bf16x2*)(Plw + a0 + 2) = bf16x2{(__bf16)p2, (__bf16)p3};
      }
      lsum += __shfl_xor(lsum, 16);
      lsum += __shfl_xor(lsum, 32);
      l_run[m] = l_run[m] * alpha + lsum;
      m_run[m] = mx;
      float ar[4];
#pragma unroll
      for (int i = 0; i < 4; ++i) ar[i] = __shfl(alpha, g * 4 + i);
#pragma unroll
      for (int dc = 0; dc < 8; ++dc)
#pragma unroll
        for (int i = 0; i < 4; ++i) oacc[m][dc][i] *= ar[i];
    }

#pragma unroll
    for (int ks = 0; ks < 2; ++ks) {
      bf16x8 pf0 = *(const bf16x8*)(Plw + (q16)*64 + (((ks * 4 + g) ^ sw) << 3));
      bf16x8 pf1 = *(const bf16x8*)(Plw + (16 + q16) * 64 + (((ks * 4 + g) ^ sw) << 3));
#pragma unroll
      for (int dc = 0; dc < 8; ++dc) {
        bf16x8 vf = *(const bf16x8*)(Vc + (dc * 16 + q16) * 64 + (((ks * 4 + g) ^ sw) << 3));
        oacc[0][dc] = __builtin_amdgcn_mfma_f32_16x16x32_bf16(pf0, vf, oacc[0][dc], 0, 0, 0);
        oacc[1][dc] = __builtin_amdgcn_mfma_f32_16x16x32_bf16(pf1, vf, oacc[1][dc], 0, 0, 0);
      }
    }

    __syncthreads();
    cur ^= 1;
  }

  const int rowbase = (b << 10) + qt * 128 + wave * 32;
#pragma unroll
  for (int m = 0; m < 2; ++m) {
    float lr[4];
#pragma unroll
    for (int i = 0; i < 4; ++i) lr[i] = __shfl(l_run[m], g * 4 + i);
#pragma unroll
    for (int dc = 0; dc < 8; ++dc)
#pragma unroll
      for (int i = 0; i < 4; ++i) {
        int row = rowbase + m * 16 + g * 4 + i;
        int col = (h << 7) + dc * 16 + q16;
        Ob[(size_t)row * 4096 + col] = (__bf16)(oacc[m][dc][i] / lr[i]);
      }
  }
#undef STAGE_KV
}

// ---------------------------------------------------------------------------
extern "C" void kernel_launch(void* const* d_in, const int* in_sizes, int n_in,
                              void* d_out, int out_size, void* d_ws,
                              size_t ws_size, hipStream_t stream) {
  const float* hidden = (const float*)d_in[0];  // [2,1024,4096] f32
  const float* cosb = (const float*)d_in[1];    // [2,1024,128] f32
  const float* sinb = (const float*)d_in[2];    // [2,1024,128] f32
  // d_in[3]: attention_mask, all-true -> ignored
  const float* w_qkv = (const float*)d_in[4];   // [6144,4096] f32
  const float* w_qn = (const float*)d_in[5];    // [128] f32
  const float* w_kn = (const float*)d_in[6];    // [128] f32
  const float* w_o = (const float*)d_in[7];     // [4096,4096] f32
  float* out = (float*)d_out;                   // [2,1024,4096] f32

  char* ws = (char*)d_ws;
  // region0 (50.3 MB): wqkvb; after QKV GEMM reused as wob (33.5) + qb (16.8)
  bf16_t* wqkvb = (bf16_t*)ws;
  bf16_t* wob = (bf16_t*)ws;
  bf16_t* qb = (bf16_t*)(ws + 33554432);
  // region1 (16.8 MB): hb; after QKV GEMM reused as attno
  bf16_t* hb = (bf16_t*)(ws + 50331648);
  bf16_t* attno = hb;
  // region2 (25.2 MB): qkv
  bf16_t* qkv = (bf16_t*)(ws + 67108864);
  // region3: kb (4.2) + vt (4.2)  -> total 100.7 MB (round-6 footprint)
  bf16_t* kb = (bf16_t*)(ws + 92274688);
  bf16_t* vt = (bf16_t*)(ws + 96468992);

  // hidden + w_qkv conversions in one launch (disjoint dst, both pre-GEMM)
  cvt_f32_bf16_2<<<dim3(16384), dim3(256), 0, stream>>>(
      hidden, hb, 8388608, w_qkv, wqkvb, 25165824);
  gemm128<3, 4, bf16_t><<<dim3(512), dim3(512), 0, stream>>>(hb, wqkvb, qkv, 2048, 6144, 4096);
  cvt_f32_bf16<<<dim3(8192), dim3(256), 0, stream>>>(w_o, wob, 16777216);
  rope_scatter<<<dim3(2048), dim3(256), 0, stream>>>(qkv, cosb, sinb, w_qn, w_kn, qb, kb, vt);
  attn_fwd<<<dim3(64 * 8), dim3(256), 0, stream>>>(qb, kb, vt, attno);
  gemm128<2, 4, float><<<dim3(512), dim3(512), 0, stream>>>(attno, wob, out, 2048, 4096, 4096);
}

// Round 14
// 278.541 us; speedup vs baseline: 1.1911x; 1.0059x over previous
//
#include <hip/hip_runtime.h>
#include <hip/hip_bf16.h>

typedef __bf16 bf16_t;
typedef bf16_t bf16x2 __attribute__((ext_vector_type(2)));
typedef bf16_t bf16x4 __attribute__((ext_vector_type(4)));
typedef bf16_t bf16x8 __attribute__((ext_vector_type(8)));
typedef float f32x4 __attribute__((ext_vector_type(4)));

#define DEVI __device__ __forceinline__

DEVI void gld_lds16(const void* g, void* l) {
  __builtin_amdgcn_global_load_lds(
      (const __attribute__((address_space(1))) void*)g,
      (__attribute__((address_space(3))) void*)l, 16, 0, 0);
}

// ---------------------------------------------------------------------------
// f32 -> bf16 conversion, 8 elements/thread.
// ---------------------------------------------------------------------------
__global__ __launch_bounds__(256) void cvt_f32_bf16(
    const float* __restrict__ in, bf16_t* __restrict__ out, long n) {
  long i = ((long)blockIdx.x * 256 + threadIdx.x) * 8;
  if (i >= n) return;
  float4 a = *(const float4*)(in + i);
  float4 b = *(const float4*)(in + i + 4);
  bf16x8 v = {(__bf16)a.x, (__bf16)a.y, (__bf16)a.z, (__bf16)a.w,
              (__bf16)b.x, (__bf16)b.y, (__bf16)b.z, (__bf16)b.w};
  *(bf16x8*)(out + i) = v;
}

// Two-segment variant: converts a (na elems) then b (nb elems) in one launch.
__global__ __launch_bounds__(256) void cvt_f32_bf16_2(
    const float* __restrict__ ina, bf16_t* __restrict__ outa, long na,
    const float* __restrict__ inb, bf16_t* __restrict__ outb, long nb) {
  long i = ((long)blockIdx.x * 256 + threadIdx.x) * 8;
  const float* src;
  bf16_t* dst;
  if (i < na) {
    src = ina + i;
    dst = outa + i;
  } else {
    long j = i - na;
    if (j >= nb) return;
    src = inb + j;
    dst = outb + j;
  }
  float4 a = *(const float4*)src;
  float4 b = *(const float4*)(src + 4);
  bf16x8 v = {(__bf16)a.x, (__bf16)a.y, (__bf16)a.z, (__bf16)a.w,
              (__bf16)b.x, (__bf16)b.y, (__bf16)b.z, (__bf16)b.w};
  *(bf16x8*)dst = v;
}

// ---------------------------------------------------------------------------
// Round-6-validated 128 x (64*FC) all-bf16 GEMM (92 us QKV @ FC=3, grid 512;
// ~72 us out-proj @ FC=2, grid 512).  8 waves (2M x 4N), BK=64, LDS
// double-buffered, XOR swizzle (16B slot ^ row&7) via pre-swizzled global
// source + linear LDS dest (global_load_lds).  Ledger: prologue
// T0.A+T0.B+T1.A vmcnt(2); t.p1 stage T+1.B (other buf); t.p2 stage T+2.A
// (cur buf); gate vmcnt(2) at p2, tail vmcnt(0).  XCD supertiling 2x4.
// Requires grid==nM*nN, nM%2==0, nN%4==0, K%64==0, K>=192.
// ---------------------------------------------------------------------------
template <int FC, int MINW, typename CT>
__global__ __launch_bounds__(512, MINW) void gemm128(
    const bf16_t* __restrict__ A, const bf16_t* __restrict__ W,
    CT* __restrict__ C, int M, int N, int K) {
  constexpr int BN = FC * 64;
  constexpr int P1 = FC / 2, P2 = FC - P1;
  __shared__ __align__(16) bf16_t As[2][128 * 64];
  __shared__ __align__(16) bf16_t Bs[2][BN * 64];
  const int tid = threadIdx.x, wave = tid >> 6, lane = tid & 63;
  const int q16 = lane & 15, gq = lane >> 4, sw = q16 & 7;
  const int wm = wave >> 2, wn = wave & 3;
  const int nM = M >> 7, nN = N / BN;
  const int cM = nM >> 1, cN = nN >> 2;
  const int xcd = (int)blockIdx.x & 7, wi = (int)blockIdx.x >> 3;
  const int tm = ((xcd >> 2) * cM + wi / cN) << 7;
  const int tn = ((xcd & 3) * cN + wi % cN) * BN;
  const int NT = K >> 6;
  const bf16_t* Ag = A + (size_t)tm * K;
  const bf16_t* Wg = W + (size_t)tn * K;
  const int sr = (wave << 3) + (lane >> 3);
  const int scol = (((lane & 7) ^ (sr & 7)) << 3);

#define STG(gbase, kq, uu, ldsbuf)                              \
  gld_lds16((gbase) + (size_t)((uu)*64 + sr) * K + (kq) + scol, \
            &(ldsbuf)[0] + (uu)*4096 + (wave << 9))

  f32x4 acc[4][FC];
#pragma unroll
  for (int i = 0; i < 4; ++i)
#pragma unroll
    for (int j = 0; j < FC; ++j) acc[i][j] = f32x4{0.f, 0.f, 0.f, 0.f};

  STG(Ag, 0, 0, As[0]);
  STG(Ag, 0, 1, As[0]);
#pragma unroll
  for (int u = 0; u < FC; ++u) STG(Wg, 0, u, Bs[0]);
  STG(Ag, 64, 0, As[1]);
  STG(Ag, 64, 1, As[1]);
  asm volatile("s_waitcnt vmcnt(2)" ::: "memory");
  __builtin_amdgcn_s_barrier();

  for (int t = 0; t < NT; ++t) {
    const int cur = t & 1;
    const bf16_t* Acur = As[cur];
    const bf16_t* Bcur = Bs[cur];
    const int k1 = (t + 1) << 6, k2 = (t + 2) << 6;
    bf16x8 afr[4][2];

#pragma unroll
    for (int fr = 0; fr < 4; ++fr) {
      const bf16_t* rp = Acur + (wm * 64 + fr * 16 + q16) * 64;
      afr[fr][0] = *(const bf16x8*)(rp + ((gq ^ sw) << 3));
      afr[fr][1] = *(const bf16x8*)(rp + (((4 + gq) ^ sw) << 3));
    }
    bf16x8 b1[P1][2];
#pragma unroll
    for (int fc = 0; fc < P1; ++fc) {
      const bf16_t* rp = Bcur + (wn * (16 * FC) + fc * 16 + q16) * 64;
      b1[fc][0] = *(const bf16x8*)(rp + ((gq ^ sw) << 3));
      b1[fc][1] = *(const bf16x8*)(rp + (((4 + gq) ^ sw) << 3));
    }
    if (t + 1 < NT) {
#pragma unroll
      for (int u = 0; u < FC; ++u) STG(Wg, k1, u, Bs[cur ^ 1]);
    }
    __builtin_amdgcn_s_barrier();
    __builtin_amdgcn_s_setprio(1);
#pragma unroll
    for (int fr = 0; fr < 4; ++fr)
#pragma unroll
      for (int fc = 0; fc < P1; ++fc)
#pragma unroll
        for (int kk = 0; kk < 2; ++kk)
          acc[fr][fc] = __builtin_amdgcn_mfma_f32_16x16x32_bf16(
              afr[fr][kk], b1[fc][kk], acc[fr][fc], 0, 0, 0);
    __builtin_amdgcn_s_setprio(0);
    asm volatile("" ::: "memory");
    __builtin_amdgcn_s_barrier();

    bf16x8 b2[P2][2];
#pragma unroll
    for (int f2 = 0; f2 < P2; ++f2) {
      const bf16_t* rp = Bcur + (wn * (16 * FC) + (P1 + f2) * 16 + q16) * 64;
      b2[f2][0] = *(const bf16x8*)(rp + ((gq ^ sw) << 3));
      b2[f2][1] = *(const bf16x8*)(rp + (((4 + gq) ^ sw) << 3));
    }
    if (t + 2 < NT) {
      STG(Ag, k2, 0, As[cur]);
      STG(Ag, k2, 1, As[cur]);
    }
    __builtin_amdgcn_s_barrier();
    __builtin_amdgcn_s_setprio(1);
#pragma unroll
    for (int fr = 0; fr < 4; ++fr)
#pragma unroll
      for (int f2 = 0; f2 < P2; ++f2)
#pragma unroll
        for (int kk = 0; kk < 2; ++kk)
          acc[fr][P1 + f2] = __builtin_amdgcn_mfma_f32_16x16x32_bf16(
              afr[fr][kk], b2[f2][kk], acc[fr][P1 + f2], 0, 0, 0);
    __builtin_amdgcn_s_setprio(0);
    if (t + 2 < NT)
      asm volatile("s_waitcnt vmcnt(2)" ::: "memory");
    else
      asm volatile("s_waitcnt vmcnt(0)" ::: "memory");
    __builtin_amdgcn_s_barrier();
  }

#pragma unroll
  for (int fr = 0; fr < 4; ++fr)
#pragma unroll
    for (int fc = 0; fc < FC; ++fc)
#pragma unroll
      for (int i = 0; i < 4; ++i) {
        int row = tm + wm * 64 + fr * 16 + gq * 4 + i;
        int col = tn + wn * (16 * FC) + fc * 16 + q16;
        C[(size_t)row * N + col] = (CT)acc[fr][fc][i];
      }
#undef STG
}

// ---------------------------------------------------------------------------
// RMSNorm + RoPE + scatter (unchanged, validated).
// ---------------------------------------------------------------------------
__global__ __launch_bounds__(256) void rope_scatter(
    const bf16_t* __restrict__ qkv, const float* __restrict__ cosb,
    const float* __restrict__ sinb, const float* __restrict__ wq,
    const float* __restrict__ wk, bf16_t* __restrict__ qb,
    bf16_t* __restrict__ kb, bf16_t* __restrict__ vt) {
  const int row = blockIdx.x;  // b*1024 + s
  const int b = row >> 10, s = row & 1023;
  const int wave = threadIdx.x >> 6, lane = threadIdx.x & 63;
  const int d0 = 2 * lane;
  const float c0 = cosb[(size_t)row * 128 + d0];
  const float c1 = cosb[(size_t)row * 128 + d0 + 1];
  const float s0 = sinb[(size_t)row * 128 + d0];
  const float s1 = sinb[(size_t)row * 128 + d0 + 1];
  const float g0q = wq[d0], g1q = wq[d0 + 1];
  const float g0k = wk[d0], g1k = wk[d0 + 1];
  const float sign = (lane < 32) ? -1.f : 1.f;

  for (int h = wave; h < 32; h += 4) {
    const bf16_t* x = qkv + (size_t)row * 6144 + h * 128 + d0;
    float x0 = (float)x[0], x1 = (float)x[1];
    float ss = x0 * x0 + x1 * x1;
#pragma unroll
    for (int off = 1; off < 64; off <<= 1) ss += __shfl_xor(ss, off);
    float r = rsqrtf(ss * (1.0f / 128.0f) + 1e-6f);
    float n0 = x0 * r * g0q, n1 = x1 * r * g1q;
    float o0 = __shfl_xor(n0, 32), o1 = __shfl_xor(n1, 32);
    float y0 = n0 * c0 + sign * o0 * s0;
    float y1 = n1 * c1 + sign * o1 * s1;
    bf16_t* dst = qb + ((size_t)(b * 32 + h) * 1024 + s) * 128 + d0;
    dst[0] = (__bf16)y0;
    dst[1] = (__bf16)y1;
  }
  for (int h = wave; h < 8; h += 4) {
    const bf16_t* x = qkv + (size_t)row * 6144 + 4096 + h * 128 + d0;
    float x0 = (float)x[0], x1 = (float)x[1];
    float ss = x0 * x0 + x1 * x1;
#pragma unroll
    for (int off = 1; off < 64; off <<= 1) ss += __shfl_xor(ss, off);
    float r = rsqrtf(ss * (1.0f / 128.0f) + 1e-6f);
    float n0 = x0 * r * g0k, n1 = x1 * r * g1k;
    float o0 = __shfl_xor(n0, 32), o1 = __shfl_xor(n1, 32);
    float y0 = n0 * c0 + sign * o0 * s0;
    float y1 = n1 * c1 + sign * o1 * s1;
    bf16_t* dst = kb + ((size_t)(b * 8 + h) * 1024 + s) * 128 + d0;
    dst[0] = (__bf16)y0;
    dst[1] = (__bf16)y1;
  }
  for (int h = wave; h < 8; h += 4) {
    const bf16_t* x = qkv + (size_t)row * 6144 + 5120 + h * 128 + d0;
    bf16_t* dst = vt + ((size_t)(b * 8 + h) * 128 + d0) * 1024 + s;
    dst[0] = x[0];
    dst[1024] = x[1];
  }
}

// ---------------------------------------------------------------------------
// Flash attention (round-3-validated structure: K AND V staged in LDS,
// double-buffered, swizzled; per-wave swizzled P tile; 1 barrier/tile).
// Round-14 micro-opts: setprio around MFMA clusters (T5, m191 +4-7% attn),
// defer-max rescale threshold (T13, +5%), b64 P-stores.
// ---------------------------------------------------------------------------
__global__ __launch_bounds__(256, 2) void attn_fwd(
    const bf16_t* __restrict__ Qb, const bf16_t* __restrict__ Kb,
    const bf16_t* __restrict__ Vt, bf16_t* __restrict__ Ob) {
  __shared__ __align__(16) bf16_t Kl[2][64 * 128];
  __shared__ __align__(16) bf16_t Vl[2][128 * 64];
  __shared__ __align__(16) bf16_t Pl[4][32 * 64];
  const int tid = threadIdx.x, wave = tid >> 6, lane = tid & 63;
  const int q16 = lane & 15, g = lane >> 4;
  const int bid = blockIdx.x;
  const int bh = bid >> 3, qt = bid & 7;
  const int b = bh >> 5, h = bh & 31;
  const int kvh = (b << 3) + (h >> 2);
  const bf16_t* qp = Qb + ((size_t)bh * 1024 + qt * 128 + wave * 32) * 128;
  const bf16_t* kp = Kb + (size_t)kvh * (1024 * 128);
  const bf16_t* vp = Vt + (size_t)kvh * (128 * 1024);
  const float SCALE = 0.088388347648318447f;
  const float RESC_THR = 8.0f;  // defer-max threshold (HK uses 8)
  const int sw = q16 & 7;

  bf16x8 qf[2][4];
#pragma unroll
  for (int m = 0; m < 2; ++m)
#pragma unroll
    for (int kc = 0; kc < 4; ++kc)
      qf[m][kc] = *(const bf16x8*)(qp + (m * 16 + q16) * 128 + kc * 32 + g * 8);

  f32x4 oacc[2][8];
#pragma unroll
  for (int m = 0; m < 2; ++m)
#pragma unroll
    for (int dc = 0; dc < 8; ++dc) oacc[m][dc] = f32x4{0.f, 0.f, 0.f, 0.f};
  float m_run[2] = {-3.0e38f, -3.0e38f}, l_run[2] = {0.f, 0.f};

#define STAGE_KV(buf, jj)                                                      \
  {                                                                            \
    _Pragma("unroll") for (int i = 0; i < 4; ++i) {                            \
      int n = (wave * 4 + i) * 64 + lane;                                      \
      int rk = n >> 4, ck = (n & 15) ^ (rk & 7);                               \
      gld_lds16(kp + (size_t)((jj) + rk) * 128 + ck * 8,                       \
                &Kl[buf][0] + (wave * 4 + i) * 512);                           \
      int rv = n >> 3, cv = (n & 7) ^ (rv & 7);                                \
      gld_lds16(vp + (size_t)rv * 1024 + (jj) + cv * 8,                        \
                &Vl[buf][0] + (wave * 4 + i) * 512);                           \
    }                                                                          \
  }

  STAGE_KV(0, 0);
  __syncthreads();
  int cur = 0;

  for (int jt = 0; jt < 16; ++jt) {
    if (jt < 15) STAGE_KV(cur ^ 1, (jt + 1) * 64);

    const bf16_t* Kc = &Kl[cur][0];
    const bf16_t* Vc = &Vl[cur][0];
    bf16_t* Plw = &Pl[wave][0];

    f32x4 st[2][4];
#pragma unroll
    for (int m = 0; m < 2; ++m)
#pragma unroll
      for (int t = 0; t < 4; ++t) st[m][t] = f32x4{0.f, 0.f, 0.f, 0.f};
#pragma unroll
    for (int t = 0; t < 4; ++t) {
      bf16x8 kf[4];
#pragma unroll
      for (int kc = 0; kc < 4; ++kc)
        kf[kc] = *(const bf16x8*)(Kc + (t * 16 + q16) * 128 + (((kc * 4 + g) ^ sw) << 3));
      __builtin_amdgcn_s_setprio(1);
#pragma unroll
      for (int m = 0; m < 2; ++m)
#pragma unroll
        for (int kc = 0; kc < 4; ++kc)
          st[m][t] = __builtin_amdgcn_mfma_f32_16x16x32_bf16(kf[kc], qf[m][kc], st[m][t], 0, 0, 0);
      __builtin_amdgcn_s_setprio(0);
    }

#pragma unroll
    for (int m = 0; m < 2; ++m) {
      float mxt = -3.0e38f;
#pragma unroll
      for (int t = 0; t < 4; ++t)
#pragma unroll
        for (int i = 0; i < 4; ++i) {
          float s = st[m][t][i] * SCALE;
          st[m][t][i] = s;
          mxt = fmaxf(mxt, s);
        }
      mxt = fmaxf(mxt, __shfl_xor(mxt, 16));
      mxt = fmaxf(mxt, __shfl_xor(mxt, 32));
      // defer-max: skip rescale when tile max stays within THR of running max
      const bool keep = __all(mxt - m_run[m] <= RESC_THR);
      const float mnew = keep ? m_run[m] : fmaxf(m_run[m], mxt);
      float lsum = 0.f;
      const int prow = m * 16 + q16;
#pragma unroll
      for (int t = 0; t < 4; ++t) {
        float p0 = __expf(st[m][t][0] - mnew);
        float p1 = __expf(st[m][t][1] - mnew);
        float p2 = __expf(st[m][t][2] - mnew);
        float p3 = __expf(st[m][t][3] - mnew);
        lsum += (p0 + p1) + (p2 + p3);
        int k0 = t * 16 + g * 4;
        int a0 = prow * 64 + ((((k0 >> 3)) ^ sw) << 3) + (k0 & 7);
        *(bf16x4*)(Plw + a0) = bf16x4{(__bf16)p0, (__bf16)p1, (__bf16)p2, (__bf16)p3};
      }
      lsum += __shfl_xor(lsum, 16);
      lsum += __shfl_xor(lsum, 32);
      if (keep) {
        l_run[m] += lsum;
      } else {
        float alpha = __expf(m_run[m] - mnew);
        l_run[m] = l_run[m] * alpha + lsum;
        m_run[m] = mnew;
        float ar[4];
#pragma unroll
        for (int i = 0; i < 4; ++i) ar[i] = __shfl(alpha, g * 4 + i);
#pragma unroll
        for (int dc = 0; dc < 8; ++dc)
#pragma unroll
          for (int i = 0; i < 4; ++i) oacc[m][dc][i] *= ar[i];
      }
    }

#pragma unroll
    for (int ks = 0; ks < 2; ++ks) {
      bf16x8 pf0 = *(const bf16x8*)(Plw + (q16)*64 + (((ks * 4 + g) ^ sw) << 3));
      bf16x8 pf1 = *(const bf16x8*)(Plw + (16 + q16) * 64 + (((ks * 4 + g) ^ sw) << 3));
      __builtin_amdgcn_s_setprio(1);
#pragma unroll
      for (int dc = 0; dc < 8; ++dc) {
        bf16x8 vf = *(const bf16x8*)(Vc + (dc * 16 + q16) * 64 + (((ks * 4 + g) ^ sw) << 3));
        oacc[0][dc] = __builtin_amdgcn_mfma_f32_16x16x32_bf16(pf0, vf, oacc[0][dc], 0, 0, 0);
        oacc[1][dc] = __builtin_amdgcn_mfma_f32_16x16x32_bf16(pf1, vf, oacc[1][dc], 0, 0, 0);
      }
      __builtin_amdgcn_s_setprio(0);
    }

    __syncthreads();
    cur ^= 1;
  }

  const int rowbase = (b << 10) + qt * 128 + wave * 32;
#pragma unroll
  for (int m = 0; m < 2; ++m) {
    float lr[4];
#pragma unroll
    for (int i = 0; i < 4; ++i) lr[i] = __shfl(l_run[m], g * 4 + i);
#pragma unroll
    for (int dc = 0; dc < 8; ++dc)
#pragma unroll
      for (int i = 0; i < 4; ++i) {
        int row = rowbase + m * 16 + g * 4 + i;
        int col = (h << 7) + dc * 16 + q16;
        Ob[(size_t)row * 4096 + col] = (__bf16)(oacc[m][dc][i] / lr[i]);
      }
  }
#undef STAGE_KV
}

// ---------------------------------------------------------------------------
extern "C" void kernel_launch(void* const* d_in, const int* in_sizes, int n_in,
                              void* d_out, int out_size, void* d_ws,
                              size_t ws_size, hipStream_t stream) {
  const float* hidden = (const float*)d_in[0];  // [2,1024,4096] f32
  const float* cosb = (const float*)d_in[1];    // [2,1024,128] f32
  const float* sinb = (const float*)d_in[2];    // [2,1024,128] f32
  // d_in[3]: attention_mask, all-true -> ignored
  const float* w_qkv = (const float*)d_in[4];   // [6144,4096] f32
  const float* w_qn = (const float*)d_in[5];    // [128] f32
  const float* w_kn = (const float*)d_in[6];    // [128] f32
  const float* w_o = (const float*)d_in[7];     // [4096,4096] f32
  float* out = (float*)d_out;                   // [2,1024,4096] f32

  char* ws = (char*)d_ws;
  // region0 (50.3 MB): wqkvb; after QKV GEMM reused as wob (33.5) + qb (16.8)
  bf16_t* wqkvb = (bf16_t*)ws;
  bf16_t* wob = (bf16_t*)ws;
  bf16_t* qb = (bf16_t*)(ws + 33554432);
  // region1 (16.8 MB): hb; after QKV GEMM reused as attno
  bf16_t* hb = (bf16_t*)(ws + 50331648);
  bf16_t* attno = hb;
  // region2 (25.2 MB): qkv
  bf16_t* qkv = (bf16_t*)(ws + 67108864);
  // region3: kb (4.2) + vt (4.2)  -> total 100.7 MB (round-6 footprint)
  bf16_t* kb = (bf16_t*)(ws + 92274688);
  bf16_t* vt = (bf16_t*)(ws + 96468992);

  cvt_f32_bf16_2<<<dim3(16384), dim3(256), 0, stream>>>(
      hidden, hb, 8388608, w_qkv, wqkvb, 25165824);
  gemm128<3, 4, bf16_t><<<dim3(512), dim3(512), 0, stream>>>(hb, wqkvb, qkv, 2048, 6144, 4096);
  cvt_f32_bf16<<<dim3(8192), dim3(256), 0, stream>>>(w_o, wob, 16777216);
  rope_scatter<<<dim3(2048), dim3(256), 0, stream>>>(qkv, cosb, sinb, w_qn, w_kn, qb, kb, vt);
  attn_fwd<<<dim3(64 * 8), dim3(256), 0, stream>>>(qb, kb, vt, attno);
  gemm128<2, 4, float><<<dim3(512), dim3(512), 0, stream>>>(attno, wob, out, 2048, 4096, 4096);
}

// Round 15
// 275.762 us; speedup vs baseline: 1.2031x; 1.0101x over previous
//
#include <hip/hip_runtime.h>
#include <hip/hip_bf16.h>

typedef __bf16 bf16_t;
typedef bf16_t bf16x2 __attribute__((ext_vector_type(2)));
typedef bf16_t bf16x4 __attribute__((ext_vector_type(4)));
typedef bf16_t bf16x8 __attribute__((ext_vector_type(8)));
typedef float f32x4 __attribute__((ext_vector_type(4)));

#define DEVI __device__ __forceinline__

DEVI void gld_lds16(const void* g, void* l) {
  __builtin_amdgcn_global_load_lds(
      (const __attribute__((address_space(1))) void*)g,
      (__attribute__((address_space(3))) void*)l, 16, 0, 0);
}

// ---------------------------------------------------------------------------
// f32 -> bf16 conversion, 8 elements/thread.
// ---------------------------------------------------------------------------
__global__ __launch_bounds__(256) void cvt_f32_bf16(
    const float* __restrict__ in, bf16_t* __restrict__ out, long n) {
  long i = ((long)blockIdx.x * 256 + threadIdx.x) * 8;
  if (i >= n) return;
  float4 a = *(const float4*)(in + i);
  float4 b = *(const float4*)(in + i + 4);
  bf16x8 v = {(__bf16)a.x, (__bf16)a.y, (__bf16)a.z, (__bf16)a.w,
              (__bf16)b.x, (__bf16)b.y, (__bf16)b.z, (__bf16)b.w};
  *(bf16x8*)(out + i) = v;
}

// Two-segment variant: converts a (na elems) then b (nb elems) in one launch.
__global__ __launch_bounds__(256) void cvt_f32_bf16_2(
    const float* __restrict__ ina, bf16_t* __restrict__ outa, long na,
    const float* __restrict__ inb, bf16_t* __restrict__ outb, long nb) {
  long i = ((long)blockIdx.x * 256 + threadIdx.x) * 8;
  const float* src;
  bf16_t* dst;
  if (i < na) {
    src = ina + i;
    dst = outa + i;
  } else {
    long j = i - na;
    if (j >= nb) return;
    src = inb + j;
    dst = outb + j;
  }
  float4 a = *(const float4*)src;
  float4 b = *(const float4*)(src + 4);
  bf16x8 v = {(__bf16)a.x, (__bf16)a.y, (__bf16)a.z, (__bf16)a.w,
              (__bf16)b.x, (__bf16)b.y, (__bf16)b.z, (__bf16)b.w};
  *(bf16x8*)dst = v;
}

// ---------------------------------------------------------------------------
// Round-6-validated 128 x (64*FC) all-bf16 GEMM (92 us QKV @ FC=3, grid 512;
// ~72 us out-proj @ FC=2, grid 512).  8 waves (2M x 4N), BK=64, LDS
// double-buffered, XOR swizzle (16B slot ^ row&7) via pre-swizzled global
// source + linear LDS dest (global_load_lds).  Ledger: prologue
// T0.A+T0.B+T1.A vmcnt(2); t.p1 stage T+1.B (other buf); t.p2 stage T+2.A
// (cur buf); gate vmcnt(2) at p2, tail vmcnt(0).  XCD supertiling 2x4.
// Requires grid==nM*nN, nM%2==0, nN%4==0, K%64==0, K>=192.
// ---------------------------------------------------------------------------
template <int FC, int MINW, typename CT>
__global__ __launch_bounds__(512, MINW) void gemm128(
    const bf16_t* __restrict__ A, const bf16_t* __restrict__ W,
    CT* __restrict__ C, int M, int N, int K) {
  constexpr int BN = FC * 64;
  constexpr int P1 = FC / 2, P2 = FC - P1;
  __shared__ __align__(16) bf16_t As[2][128 * 64];
  __shared__ __align__(16) bf16_t Bs[2][BN * 64];
  const int tid = threadIdx.x, wave = tid >> 6, lane = tid & 63;
  const int q16 = lane & 15, gq = lane >> 4, sw = q16 & 7;
  const int wm = wave >> 2, wn = wave & 3;
  const int nM = M >> 7, nN = N / BN;
  const int cM = nM >> 1, cN = nN >> 2;
  const int xcd = (int)blockIdx.x & 7, wi = (int)blockIdx.x >> 3;
  const int tm = ((xcd >> 2) * cM + wi / cN) << 7;
  const int tn = ((xcd & 3) * cN + wi % cN) * BN;
  const int NT = K >> 6;
  const bf16_t* Ag = A + (size_t)tm * K;
  const bf16_t* Wg = W + (size_t)tn * K;
  const int sr = (wave << 3) + (lane >> 3);
  const int scol = (((lane & 7) ^ (sr & 7)) << 3);

#define STG(gbase, kq, uu, ldsbuf)                              \
  gld_lds16((gbase) + (size_t)((uu)*64 + sr) * K + (kq) + scol, \
            &(ldsbuf)[0] + (uu)*4096 + (wave << 9))

  f32x4 acc[4][FC];
#pragma unroll
  for (int i = 0; i < 4; ++i)
#pragma unroll
    for (int j = 0; j < FC; ++j) acc[i][j] = f32x4{0.f, 0.f, 0.f, 0.f};

  STG(Ag, 0, 0, As[0]);
  STG(Ag, 0, 1, As[0]);
#pragma unroll
  for (int u = 0; u < FC; ++u) STG(Wg, 0, u, Bs[0]);
  STG(Ag, 64, 0, As[1]);
  STG(Ag, 64, 1, As[1]);
  asm volatile("s_waitcnt vmcnt(2)" ::: "memory");
  __builtin_amdgcn_s_barrier();

  for (int t = 0; t < NT; ++t) {
    const int cur = t & 1;
    const bf16_t* Acur = As[cur];
    const bf16_t* Bcur = Bs[cur];
    const int k1 = (t + 1) << 6, k2 = (t + 2) << 6;
    bf16x8 afr[4][2];

#pragma unroll
    for (int fr = 0; fr < 4; ++fr) {
      const bf16_t* rp = Acur + (wm * 64 + fr * 16 + q16) * 64;
      afr[fr][0] = *(const bf16x8*)(rp + ((gq ^ sw) << 3));
      afr[fr][1] = *(const bf16x8*)(rp + (((4 + gq) ^ sw) << 3));
    }
    bf16x8 b1[P1][2];
#pragma unroll
    for (int fc = 0; fc < P1; ++fc) {
      const bf16_t* rp = Bcur + (wn * (16 * FC) + fc * 16 + q16) * 64;
      b1[fc][0] = *(const bf16x8*)(rp + ((gq ^ sw) << 3));
      b1[fc][1] = *(const bf16x8*)(rp + (((4 + gq) ^ sw) << 3));
    }
    if (t + 1 < NT) {
#pragma unroll
      for (int u = 0; u < FC; ++u) STG(Wg, k1, u, Bs[cur ^ 1]);
    }
    __builtin_amdgcn_s_barrier();
    __builtin_amdgcn_s_setprio(1);
#pragma unroll
    for (int fr = 0; fr < 4; ++fr)
#pragma unroll
      for (int fc = 0; fc < P1; ++fc)
#pragma unroll
        for (int kk = 0; kk < 2; ++kk)
          acc[fr][fc] = __builtin_amdgcn_mfma_f32_16x16x32_bf16(
              afr[fr][kk], b1[fc][kk], acc[fr][fc], 0, 0, 0);
    __builtin_amdgcn_s_setprio(0);
    asm volatile("" ::: "memory");
    __builtin_amdgcn_s_barrier();

    bf16x8 b2[P2][2];
#pragma unroll
    for (int f2 = 0; f2 < P2; ++f2) {
      const bf16_t* rp = Bcur + (wn * (16 * FC) + (P1 + f2) * 16 + q16) * 64;
      b2[f2][0] = *(const bf16x8*)(rp + ((gq ^ sw) << 3));
      b2[f2][1] = *(const bf16x8*)(rp + (((4 + gq) ^ sw) << 3));
    }
    if (t + 2 < NT) {
      STG(Ag, k2, 0, As[cur]);
      STG(Ag, k2, 1, As[cur]);
    }
    __builtin_amdgcn_s_barrier();
    __builtin_amdgcn_s_setprio(1);
#pragma unroll
    for (int fr = 0; fr < 4; ++fr)
#pragma unroll
      for (int f2 = 0; f2 < P2; ++f2)
#pragma unroll
        for (int kk = 0; kk < 2; ++kk)
          acc[fr][P1 + f2] = __builtin_amdgcn_mfma_f32_16x16x32_bf16(
              afr[fr][kk], b2[f2][kk], acc[fr][P1 + f2], 0, 0, 0);
    __builtin_amdgcn_s_setprio(0);
    if (t + 2 < NT)
      asm volatile("s_waitcnt vmcnt(2)" ::: "memory");
    else
      asm volatile("s_waitcnt vmcnt(0)" ::: "memory");
    __builtin_amdgcn_s_barrier();
  }

#pragma unroll
  for (int fr = 0; fr < 4; ++fr)
#pragma unroll
    for (int fc = 0; fc < FC; ++fc)
#pragma unroll
      for (int i = 0; i < 4; ++i) {
        int row = tm + wm * 64 + fr * 16 + gq * 4 + i;
        int col = tn + wn * (16 * FC) + fc * 16 + q16;
        C[(size_t)row * N + col] = (CT)acc[fr][fc][i];
      }
#undef STG
}

// ---------------------------------------------------------------------------
// RMSNorm + RoPE + scatter (unchanged, validated).
// ---------------------------------------------------------------------------
__global__ __launch_bounds__(256) void rope_scatter(
    const bf16_t* __restrict__ qkv, const float* __restrict__ cosb,
    const float* __restrict__ sinb, const float* __restrict__ wq,
    const float* __restrict__ wk, bf16_t* __restrict__ qb,
    bf16_t* __restrict__ kb, bf16_t* __restrict__ vt) {
  const int row = blockIdx.x;  // b*1024 + s
  const int b = row >> 10, s = row & 1023;
  const int wave = threadIdx.x >> 6, lane = threadIdx.x & 63;
  const int d0 = 2 * lane;
  const float c0 = cosb[(size_t)row * 128 + d0];
  const float c1 = cosb[(size_t)row * 128 + d0 + 1];
  const float s0 = sinb[(size_t)row * 128 + d0];
  const float s1 = sinb[(size_t)row * 128 + d0 + 1];
  const float g0q = wq[d0], g1q = wq[d0 + 1];
  const float g0k = wk[d0], g1k = wk[d0 + 1];
  const float sign = (lane < 32) ? -1.f : 1.f;

  for (int h = wave; h < 32; h += 4) {
    const bf16_t* x = qkv + (size_t)row * 6144 + h * 128 + d0;
    float x0 = (float)x[0], x1 = (float)x[1];
    float ss = x0 * x0 + x1 * x1;
#pragma unroll
    for (int off = 1; off < 64; off <<= 1) ss += __shfl_xor(ss, off);
    float r = rsqrtf(ss * (1.0f / 128.0f) + 1e-6f);
    float n0 = x0 * r * g0q, n1 = x1 * r * g1q;
    float o0 = __shfl_xor(n0, 32), o1 = __shfl_xor(n1, 32);
    float y0 = n0 * c0 + sign * o0 * s0;
    float y1 = n1 * c1 + sign * o1 * s1;
    bf16_t* dst = qb + ((size_t)(b * 32 + h) * 1024 + s) * 128 + d0;
    dst[0] = (__bf16)y0;
    dst[1] = (__bf16)y1;
  }
  for (int h = wave; h < 8; h += 4) {
    const bf16_t* x = qkv + (size_t)row * 6144 + 4096 + h * 128 + d0;
    float x0 = (float)x[0], x1 = (float)x[1];
    float ss = x0 * x0 + x1 * x1;
#pragma unroll
    for (int off = 1; off < 64; off <<= 1) ss += __shfl_xor(ss, off);
    float r = rsqrtf(ss * (1.0f / 128.0f) + 1e-6f);
    float n0 = x0 * r * g0k, n1 = x1 * r * g1k;
    float o0 = __shfl_xor(n0, 32), o1 = __shfl_xor(n1, 32);
    float y0 = n0 * c0 + sign * o0 * s0;
    float y1 = n1 * c1 + sign * o1 * s1;
    bf16_t* dst = kb + ((size_t)(b * 8 + h) * 1024 + s) * 128 + d0;
    dst[0] = (__bf16)y0;
    dst[1] = (__bf16)y1;
  }
  for (int h = wave; h < 8; h += 4) {
    const bf16_t* x = qkv + (size_t)row * 6144 + 5120 + h * 128 + d0;
    bf16_t* dst = vt + ((size_t)(b * 8 + h) * 128 + d0) * 1024 + s;
    dst[0] = x[0];
    dst[1024] = x[1];
  }
}

// ---------------------------------------------------------------------------
// Flash attention v4: same math/layouts as the validated r14 kernel, but
// re-partitioned 4 waves x 32 rows -> 8 waves x 16 rows (512 threads).
// LDS 80KB (Kl 32 + Vl 32 + Pl 16) -> 2 blocks/CU -> 16 waves/CU
// (4/SIMD, 2x the latency hiding).  Grid unchanged (64 bh x 8 qt = 512).
// Keeps T5 setprio, T13 defer-max, b64 P-stores.
// ---------------------------------------------------------------------------
__global__ __launch_bounds__(512, 4) void attn_fwd(
    const bf16_t* __restrict__ Qb, const bf16_t* __restrict__ Kb,
    const bf16_t* __restrict__ Vt, bf16_t* __restrict__ Ob) {
  __shared__ __align__(16) bf16_t Kl[2][64 * 128];   // 32KB dbuf, swizzled
  __shared__ __align__(16) bf16_t Vl[2][128 * 64];   // 32KB dbuf, swizzled
  __shared__ __align__(16) bf16_t Pl[8][16 * 64];    // 2KB/wave, swizzled
  const int tid = threadIdx.x, wave = tid >> 6, lane = tid & 63;
  const int q16 = lane & 15, g = lane >> 4;
  const int bid = blockIdx.x;
  const int bh = bid >> 3, qt = bid & 7;
  const int b = bh >> 5, h = bh & 31;
  const int kvh = (b << 3) + (h >> 2);
  const bf16_t* qp = Qb + ((size_t)bh * 1024 + qt * 128 + wave * 16) * 128;
  const bf16_t* kp = Kb + (size_t)kvh * (1024 * 128);
  const bf16_t* vp = Vt + (size_t)kvh * (128 * 1024);
  const float SCALE = 0.088388347648318447f;
  const float RESC_THR = 8.0f;
  const int sw = q16 & 7;

  bf16x8 qf[4];
#pragma unroll
  for (int kc = 0; kc < 4; ++kc)
    qf[kc] = *(const bf16x8*)(qp + q16 * 128 + kc * 32 + g * 8);

  f32x4 oacc[8];
#pragma unroll
  for (int dc = 0; dc < 8; ++dc) oacc[dc] = f32x4{0.f, 0.f, 0.f, 0.f};
  float m_run = -3.0e38f, l_run = 0.f;

  // K tile 64x128 (16 chunks of 1KB) + V^T tile 128x64 (16 chunks);
  // 8 waves -> 2 K-chunks + 2 V-chunks per wave.
#define STAGE_KV(buf, jj)                                                      \
  {                                                                            \
    _Pragma("unroll") for (int i = 0; i < 2; ++i) {                            \
      int n = (wave * 2 + i) * 64 + lane;                                      \
      int rk = n >> 4, ck = (n & 15) ^ (rk & 7);                               \
      gld_lds16(kp + (size_t)((jj) + rk) * 128 + ck * 8,                       \
                &Kl[buf][0] + (wave * 2 + i) * 512);                           \
      int rv = n >> 3, cv = (n & 7) ^ (rv & 7);                                \
      gld_lds16(vp + (size_t)rv * 1024 + (jj) + cv * 8,                        \
                &Vl[buf][0] + (wave * 2 + i) * 512);                           \
    }                                                                          \
  }

  STAGE_KV(0, 0);
  __syncthreads();
  int cur = 0;

  for (int jt = 0; jt < 16; ++jt) {
    if (jt < 15) STAGE_KV(cur ^ 1, (jt + 1) * 64);

    const bf16_t* Kc = &Kl[cur][0];
    const bf16_t* Vc = &Vl[cur][0];
    bf16_t* Plw = &Pl[wave][0];

    f32x4 st[4];
#pragma unroll
    for (int t = 0; t < 4; ++t) st[t] = f32x4{0.f, 0.f, 0.f, 0.f};
#pragma unroll
    for (int t = 0; t < 4; ++t) {
      bf16x8 kf[4];
#pragma unroll
      for (int kc = 0; kc < 4; ++kc)
        kf[kc] = *(const bf16x8*)(Kc + (t * 16 + q16) * 128 + (((kc * 4 + g) ^ sw) << 3));
      __builtin_amdgcn_s_setprio(1);
#pragma unroll
      for (int kc = 0; kc < 4; ++kc)
        st[t] = __builtin_amdgcn_mfma_f32_16x16x32_bf16(kf[kc], qf[kc], st[t], 0, 0, 0);
      __builtin_amdgcn_s_setprio(0);
    }

    {
      float mxt = -3.0e38f;
#pragma unroll
      for (int t = 0; t < 4; ++t)
#pragma unroll
        for (int i = 0; i < 4; ++i) {
          float s = st[t][i] * SCALE;
          st[t][i] = s;
          mxt = fmaxf(mxt, s);
        }
      mxt = fmaxf(mxt, __shfl_xor(mxt, 16));
      mxt = fmaxf(mxt, __shfl_xor(mxt, 32));
      const bool keep = __all(mxt - m_run <= RESC_THR);
      const float mnew = keep ? m_run : fmaxf(m_run, mxt);
      float lsum = 0.f;
#pragma unroll
      for (int t = 0; t < 4; ++t) {
        float p0 = __expf(st[t][0] - mnew);
        float p1 = __expf(st[t][1] - mnew);
        float p2 = __expf(st[t][2] - mnew);
        float p3 = __expf(st[t][3] - mnew);
        lsum += (p0 + p1) + (p2 + p3);
        int k0 = t * 16 + g * 4;
        int a0 = q16 * 64 + ((((k0 >> 3)) ^ sw) << 3) + (k0 & 7);
        *(bf16x4*)(Plw + a0) = bf16x4{(__bf16)p0, (__bf16)p1, (__bf16)p2, (__bf16)p3};
      }
      lsum += __shfl_xor(lsum, 16);
      lsum += __shfl_xor(lsum, 32);
      if (keep) {
        l_run += lsum;
      } else {
        float alpha = __expf(m_run - mnew);
        l_run = l_run * alpha + lsum;
        m_run = mnew;
        float ar[4];
#pragma unroll
        for (int i = 0; i < 4; ++i) ar[i] = __shfl(alpha, g * 4 + i);
#pragma unroll
        for (int dc = 0; dc < 8; ++dc)
#pragma unroll
          for (int i = 0; i < 4; ++i) oacc[dc][i] *= ar[i];
      }
    }

#pragma unroll
    for (int ks = 0; ks < 2; ++ks) {
      bf16x8 pf = *(const bf16x8*)(Plw + q16 * 64 + (((ks * 4 + g) ^ sw) << 3));
      __builtin_amdgcn_s_setprio(1);
#pragma unroll
      for (int dc = 0; dc < 8; ++dc) {
        bf16x8 vf = *(const bf16x8*)(Vc + (dc * 16 + q16) * 64 + (((ks * 4 + g) ^ sw) << 3));
        oacc[dc] = __builtin_amdgcn_mfma_f32_16x16x32_bf16(pf, vf, oacc[dc], 0, 0, 0);
      }
      __builtin_amdgcn_s_setprio(0);
    }

    __syncthreads();
    cur ^= 1;
  }

  const int rowbase = (b << 10) + qt * 128 + wave * 16;
  float lr[4];
#pragma unroll
  for (int i = 0; i < 4; ++i) lr[i] = __shfl(l_run, g * 4 + i);
#pragma unroll
  for (int dc = 0; dc < 8; ++dc)
#pragma unroll
    for (int i = 0; i < 4; ++i) {
      int row = rowbase + g * 4 + i;
      int col = (h << 7) + dc * 16 + q16;
      Ob[(size_t)row * 4096 + col] = (__bf16)(oacc[dc][i] / lr[i]);
    }
#undef STAGE_KV
}

// ---------------------------------------------------------------------------
extern "C" void kernel_launch(void* const* d_in, const int* in_sizes, int n_in,
                              void* d_out, int out_size, void* d_ws,
                              size_t ws_size, hipStream_t stream) {
  const float* hidden = (const float*)d_in[0];  // [2,1024,4096] f32
  const float* cosb = (const float*)d_in[1];    // [2,1024,128] f32
  const float* sinb = (const float*)d_in[2];    // [2,1024,128] f32
  // d_in[3]: attention_mask, all-true -> ignored
  const float* w_qkv = (const float*)d_in[4];   // [6144,4096] f32
  const float* w_qn = (const float*)d_in[5];    // [128] f32
  const float* w_kn = (const float*)d_in[6];    // [128] f32
  const float* w_o = (const float*)d_in[7];     // [4096,4096] f32
  float* out = (float*)d_out;                   // [2,1024,4096] f32

  char* ws = (char*)d_ws;
  // region0 (50.3 MB): wqkvb; after QKV GEMM reused as wob (33.5) + qb (16.8)
  bf16_t* wqkvb = (bf16_t*)ws;
  bf16_t* wob = (bf16_t*)ws;
  bf16_t* qb = (bf16_t*)(ws + 33554432);
  // region1 (16.8 MB): hb; after QKV GEMM reused as attno
  bf16_t* hb = (bf16_t*)(ws + 50331648);
  bf16_t* attno = hb;
  // region2 (25.2 MB): qkv
  bf16_t* qkv = (bf16_t*)(ws + 67108864);
  // region3: kb (4.2) + vt (4.2)  -> total 100.7 MB (round-6 footprint)
  bf16_t* kb = (bf16_t*)(ws + 92274688);
  bf16_t* vt = (bf16_t*)(ws + 96468992);

  cvt_f32_bf16_2<<<dim3(16384), dim3(256), 0, stream>>>(
      hidden, hb, 8388608, w_qkv, wqkvb, 25165824);
  gemm128<3, 4, bf16_t><<<dim3(512), dim3(512), 0, stream>>>(hb, wqkvb, qkv, 2048, 6144, 4096);
  cvt_f32_bf16<<<dim3(8192), dim3(256), 0, stream>>>(w_o, wob, 16777216);
  rope_scatter<<<dim3(2048), dim3(256), 0, stream>>>(qkv, cosb, sinb, w_qn, w_kn, qb, kb, vt);
  attn_fwd<<<dim3(64 * 8), dim3(512), 0, stream>>>(qb, kb, vt, attno);
  gemm128<2, 4, float><<<dim3(512), dim3(512), 0, stream>>>(attno, wob, out, 2048, 4096, 4096);
}

// Round 16
// 266.489 us; speedup vs baseline: 1.2450x; 1.0348x over previous
//
#include <hip/hip_runtime.h>
#include <hip/hip_bf16.h>

typedef __bf16 bf16_t;
typedef bf16_t bf16x2 __attribute__((ext_vector_type(2)));
typedef bf16_t bf16x4 __attribute__((ext_vector_type(4)));
typedef bf16_t bf16x8 __attribute__((ext_vector_type(8)));
typedef float f32x4 __attribute__((ext_vector_type(4)));

#define DEVI __device__ __forceinline__

DEVI void gld_lds16(const void* g, void* l) {
  __builtin_amdgcn_global_load_lds(
      (const __attribute__((address_space(1))) void*)g,
      (__attribute__((address_space(3))) void*)l, 16, 0, 0);
}

// ---------------------------------------------------------------------------
// f32 -> bf16 conversion, 8 elements/thread.
// ---------------------------------------------------------------------------
__global__ __launch_bounds__(256) void cvt_f32_bf16(
    const float* __restrict__ in, bf16_t* __restrict__ out, long n) {
  long i = ((long)blockIdx.x * 256 + threadIdx.x) * 8;
  if (i >= n) return;
  float4 a = *(const float4*)(in + i);
  float4 b = *(const float4*)(in + i + 4);
  bf16x8 v = {(__bf16)a.x, (__bf16)a.y, (__bf16)a.z, (__bf16)a.w,
              (__bf16)b.x, (__bf16)b.y, (__bf16)b.z, (__bf16)b.w};
  *(bf16x8*)(out + i) = v;
}

// Two-segment variant: converts a (na elems) then b (nb elems) in one launch.
__global__ __launch_bounds__(256) void cvt_f32_bf16_2(
    const float* __restrict__ ina, bf16_t* __restrict__ outa, long na,
    const float* __restrict__ inb, bf16_t* __restrict__ outb, long nb) {
  long i = ((long)blockIdx.x * 256 + threadIdx.x) * 8;
  const float* src;
  bf16_t* dst;
  if (i < na) {
    src = ina + i;
    dst = outa + i;
  } else {
    long j = i - na;
    if (j >= nb) return;
    src = inb + j;
    dst = outb + j;
  }
  float4 a = *(const float4*)src;
  float4 b = *(const float4*)(src + 4);
  bf16x8 v = {(__bf16)a.x, (__bf16)a.y, (__bf16)a.z, (__bf16)a.w,
              (__bf16)b.x, (__bf16)b.y, (__bf16)b.z, (__bf16)b.w};
  *(bf16x8*)dst = v;
}

// ---------------------------------------------------------------------------
// Round-6-validated 128 x (64*FC) all-bf16 GEMM (92 us QKV @ FC=3, grid 512;
// ~72 us out-proj @ FC=2, grid 512).  8 waves (2M x 4N), BK=64, LDS
// double-buffered, XOR swizzle (16B slot ^ row&7) via pre-swizzled global
// source + linear LDS dest (global_load_lds).  Ledger: prologue
// T0.A+T0.B+T1.A vmcnt(2); t.p1 stage T+1.B (other buf); t.p2 stage T+2.A
// (cur buf); gate vmcnt(2) at p2, tail vmcnt(0).  XCD supertiling 2x4.
// Requires grid==nM*nN, nM%2==0, nN%4==0, K%64==0, K>=192.
// ---------------------------------------------------------------------------
template <int FC, int MINW, typename CT>
__global__ __launch_bounds__(512, MINW) void gemm128(
    const bf16_t* __restrict__ A, const bf16_t* __restrict__ W,
    CT* __restrict__ C, int M, int N, int K) {
  constexpr int BN = FC * 64;
  constexpr int P1 = FC / 2, P2 = FC - P1;
  __shared__ __align__(16) bf16_t As[2][128 * 64];
  __shared__ __align__(16) bf16_t Bs[2][BN * 64];
  const int tid = threadIdx.x, wave = tid >> 6, lane = tid & 63;
  const int q16 = lane & 15, gq = lane >> 4, sw = q16 & 7;
  const int wm = wave >> 2, wn = wave & 3;
  const int nM = M >> 7, nN = N / BN;
  const int cM = nM >> 1, cN = nN >> 2;
  const int xcd = (int)blockIdx.x & 7, wi = (int)blockIdx.x >> 3;
  const int tm = ((xcd >> 2) * cM + wi / cN) << 7;
  const int tn = ((xcd & 3) * cN + wi % cN) * BN;
  const int NT = K >> 6;
  const bf16_t* Ag = A + (size_t)tm * K;
  const bf16_t* Wg = W + (size_t)tn * K;
  const int sr = (wave << 3) + (lane >> 3);
  const int scol = (((lane & 7) ^ (sr & 7)) << 3);

#define STG(gbase, kq, uu, ldsbuf)                              \
  gld_lds16((gbase) + (size_t)((uu)*64 + sr) * K + (kq) + scol, \
            &(ldsbuf)[0] + (uu)*4096 + (wave << 9))

  f32x4 acc[4][FC];
#pragma unroll
  for (int i = 0; i < 4; ++i)
#pragma unroll
    for (int j = 0; j < FC; ++j) acc[i][j] = f32x4{0.f, 0.f, 0.f, 0.f};

  STG(Ag, 0, 0, As[0]);
  STG(Ag, 0, 1, As[0]);
#pragma unroll
  for (int u = 0; u < FC; ++u) STG(Wg, 0, u, Bs[0]);
  STG(Ag, 64, 0, As[1]);
  STG(Ag, 64, 1, As[1]);
  asm volatile("s_waitcnt vmcnt(2)" ::: "memory");
  __builtin_amdgcn_s_barrier();

  for (int t = 0; t < NT; ++t) {
    const int cur = t & 1;
    const bf16_t* Acur = As[cur];
    const bf16_t* Bcur = Bs[cur];
    const int k1 = (t + 1) << 6, k2 = (t + 2) << 6;
    bf16x8 afr[4][2];

#pragma unroll
    for (int fr = 0; fr < 4; ++fr) {
      const bf16_t* rp = Acur + (wm * 64 + fr * 16 + q16) * 64;
      afr[fr][0] = *(const bf16x8*)(rp + ((gq ^ sw) << 3));
      afr[fr][1] = *(const bf16x8*)(rp + (((4 + gq) ^ sw) << 3));
    }
    bf16x8 b1[P1][2];
#pragma unroll
    for (int fc = 0; fc < P1; ++fc) {
      const bf16_t* rp = Bcur + (wn * (16 * FC) + fc * 16 + q16) * 64;
      b1[fc][0] = *(const bf16x8*)(rp + ((gq ^ sw) << 3));
      b1[fc][1] = *(const bf16x8*)(rp + (((4 + gq) ^ sw) << 3));
    }
    if (t + 1 < NT) {
#pragma unroll
      for (int u = 0; u < FC; ++u) STG(Wg, k1, u, Bs[cur ^ 1]);
    }
    __builtin_amdgcn_s_barrier();
    __builtin_amdgcn_s_setprio(1);
#pragma unroll
    for (int fr = 0; fr < 4; ++fr)
#pragma unroll
      for (int fc = 0; fc < P1; ++fc)
#pragma unroll
        for (int kk = 0; kk < 2; ++kk)
          acc[fr][fc] = __builtin_amdgcn_mfma_f32_16x16x32_bf16(
              afr[fr][kk], b1[fc][kk], acc[fr][fc], 0, 0, 0);
    __builtin_amdgcn_s_setprio(0);
    asm volatile("" ::: "memory");
    __builtin_amdgcn_s_barrier();

    bf16x8 b2[P2][2];
#pragma unroll
    for (int f2 = 0; f2 < P2; ++f2) {
      const bf16_t* rp = Bcur + (wn * (16 * FC) + (P1 + f2) * 16 + q16) * 64;
      b2[f2][0] = *(const bf16x8*)(rp + ((gq ^ sw) << 3));
      b2[f2][1] = *(const bf16x8*)(rp + (((4 + gq) ^ sw) << 3));
    }
    if (t + 2 < NT) {
      STG(Ag, k2, 0, As[cur]);
      STG(Ag, k2, 1, As[cur]);
    }
    __builtin_amdgcn_s_barrier();
    __builtin_amdgcn_s_setprio(1);
#pragma unroll
    for (int fr = 0; fr < 4; ++fr)
#pragma unroll
      for (int f2 = 0; f2 < P2; ++f2)
#pragma unroll
        for (int kk = 0; kk < 2; ++kk)
          acc[fr][P1 + f2] = __builtin_amdgcn_mfma_f32_16x16x32_bf16(
              afr[fr][kk], b2[f2][kk], acc[fr][P1 + f2], 0, 0, 0);
    __builtin_amdgcn_s_setprio(0);
    if (t + 2 < NT)
      asm volatile("s_waitcnt vmcnt(2)" ::: "memory");
    else
      asm volatile("s_waitcnt vmcnt(0)" ::: "memory");
    __builtin_amdgcn_s_barrier();
  }

#pragma unroll
  for (int fr = 0; fr < 4; ++fr)
#pragma unroll
    for (int fc = 0; fc < FC; ++fc)
#pragma unroll
      for (int i = 0; i < 4; ++i) {
        int row = tm + wm * 64 + fr * 16 + gq * 4 + i;
        int col = tn + wn * (16 * FC) + fc * 16 + q16;
        C[(size_t)row * N + col] = (CT)acc[fr][fc][i];
      }
#undef STG
}

// ---------------------------------------------------------------------------
// RMSNorm + RoPE + scatter (unchanged, validated).
// ---------------------------------------------------------------------------
__global__ __launch_bounds__(256) void rope_scatter(
    const bf16_t* __restrict__ qkv, const float* __restrict__ cosb,
    const float* __restrict__ sinb, const float* __restrict__ wq,
    const float* __restrict__ wk, bf16_t* __restrict__ qb,
    bf16_t* __restrict__ kb, bf16_t* __restrict__ vt) {
  const int row = blockIdx.x;  // b*1024 + s
  const int b = row >> 10, s = row & 1023;
  const int wave = threadIdx.x >> 6, lane = threadIdx.x & 63;
  const int d0 = 2 * lane;
  const float c0 = cosb[(size_t)row * 128 + d0];
  const float c1 = cosb[(size_t)row * 128 + d0 + 1];
  const float s0 = sinb[(size_t)row * 128 + d0];
  const float s1 = sinb[(size_t)row * 128 + d0 + 1];
  const float g0q = wq[d0], g1q = wq[d0 + 1];
  const float g0k = wk[d0], g1k = wk[d0 + 1];
  const float sign = (lane < 32) ? -1.f : 1.f;

  for (int h = wave; h < 32; h += 4) {
    const bf16_t* x = qkv + (size_t)row * 6144 + h * 128 + d0;
    float x0 = (float)x[0], x1 = (float)x[1];
    float ss = x0 * x0 + x1 * x1;
#pragma unroll
    for (int off = 1; off < 64; off <<= 1) ss += __shfl_xor(ss, off);
    float r = rsqrtf(ss * (1.0f / 128.0f) + 1e-6f);
    float n0 = x0 * r * g0q, n1 = x1 * r * g1q;
    float o0 = __shfl_xor(n0, 32), o1 = __shfl_xor(n1, 32);
    float y0 = n0 * c0 + sign * o0 * s0;
    float y1 = n1 * c1 + sign * o1 * s1;
    bf16_t* dst = qb + ((size_t)(b * 32 + h) * 1024 + s) * 128 + d0;
    dst[0] = (__bf16)y0;
    dst[1] = (__bf16)y1;
  }
  for (int h = wave; h < 8; h += 4) {
    const bf16_t* x = qkv + (size_t)row * 6144 + 4096 + h * 128 + d0;
    float x0 = (float)x[0], x1 = (float)x[1];
    float ss = x0 * x0 + x1 * x1;
#pragma unroll
    for (int off = 1; off < 64; off <<= 1) ss += __shfl_xor(ss, off);
    float r = rsqrtf(ss * (1.0f / 128.0f) + 1e-6f);
    float n0 = x0 * r * g0k, n1 = x1 * r * g1k;
    float o0 = __shfl_xor(n0, 32), o1 = __shfl_xor(n1, 32);
    float y0 = n0 * c0 + sign * o0 * s0;
    float y1 = n1 * c1 + sign * o1 * s1;
    bf16_t* dst = kb + ((size_t)(b * 8 + h) * 1024 + s) * 128 + d0;
    dst[0] = (__bf16)y0;
    dst[1] = (__bf16)y1;
  }
  for (int h = wave; h < 8; h += 4) {
    const bf16_t* x = qkv + (size_t)row * 6144 + 5120 + h * 128 + d0;
    bf16_t* dst = vt + ((size_t)(b * 8 + h) * 128 + d0) * 1024 + s;
    dst[0] = x[0];
    dst[1024] = x[1];
  }
}

// ---------------------------------------------------------------------------
// Flash attention v5 = v4 (8 waves x 16 rows, validated r15) + fused w_o
// f32->bf16 conversion interleaved per kv-tile (1 float4 load + 1 bf16x4
// store per thread per tile) -- rides attention's idle memory pipe.
// 512 blocks x 16 tiles x 512 threads x 4 elems == 16,777,216 elems exact.
// ---------------------------------------------------------------------------
__global__ __launch_bounds__(512, 4) void attn_fwd(
    const bf16_t* __restrict__ Qb, const bf16_t* __restrict__ Kb,
    const bf16_t* __restrict__ Vt, bf16_t* __restrict__ Ob,
    const float* __restrict__ wo_src, bf16_t* __restrict__ wo_dst) {
  __shared__ __align__(16) bf16_t Kl[2][64 * 128];
  __shared__ __align__(16) bf16_t Vl[2][128 * 64];
  __shared__ __align__(16) bf16_t Pl[8][16 * 64];
  const int tid = threadIdx.x, wave = tid >> 6, lane = tid & 63;
  const int q16 = lane & 15, g = lane >> 4;
  const int bid = blockIdx.x;
  const int bh = bid >> 3, qt = bid & 7;
  const int b = bh >> 5, h = bh & 31;
  const int kvh = (b << 3) + (h >> 2);
  const bf16_t* qp = Qb + ((size_t)bh * 1024 + qt * 128 + wave * 16) * 128;
  const bf16_t* kp = Kb + (size_t)kvh * (1024 * 128);
  const bf16_t* vp = Vt + (size_t)kvh * (128 * 1024);
  const float SCALE = 0.088388347648318447f;
  const float RESC_THR = 8.0f;
  const int sw = q16 & 7;

  bf16x8 qf[4];
#pragma unroll
  for (int kc = 0; kc < 4; ++kc)
    qf[kc] = *(const bf16x8*)(qp + q16 * 128 + kc * 32 + g * 8);

  f32x4 oacc[8];
#pragma unroll
  for (int dc = 0; dc < 8; ++dc) oacc[dc] = f32x4{0.f, 0.f, 0.f, 0.f};
  float m_run = -3.0e38f, l_run = 0.f;

#define STAGE_KV(buf, jj)                                                      \
  {                                                                            \
    _Pragma("unroll") for (int i = 0; i < 2; ++i) {                            \
      int n = (wave * 2 + i) * 64 + lane;                                      \
      int rk = n >> 4, ck = (n & 15) ^ (rk & 7);                               \
      gld_lds16(kp + (size_t)((jj) + rk) * 128 + ck * 8,                       \
                &Kl[buf][0] + (wave * 2 + i) * 512);                           \
      int rv = n >> 3, cv = (n & 7) ^ (rv & 7);                                \
      gld_lds16(vp + (size_t)rv * 1024 + (jj) + cv * 8,                        \
                &Vl[buf][0] + (wave * 2 + i) * 512);                           \
    }                                                                          \
  }

  STAGE_KV(0, 0);
  __syncthreads();
  int cur = 0;

  for (int jt = 0; jt < 16; ++jt) {
    if (jt < 15) STAGE_KV(cur ^ 1, (jt + 1) * 64);

    // fused w_o convert: one float4 in, one bf16x4 out per thread per tile.
    {
      long ci = (((long)bid * 16 + jt) * 512 + tid) * 4;
      float4 w4 = *(const float4*)(wo_src + ci);
      *(bf16x4*)(wo_dst + ci) =
          bf16x4{(__bf16)w4.x, (__bf16)w4.y, (__bf16)w4.z, (__bf16)w4.w};
    }

    const bf16_t* Kc = &Kl[cur][0];
    const bf16_t* Vc = &Vl[cur][0];
    bf16_t* Plw = &Pl[wave][0];

    f32x4 st[4];
#pragma unroll
    for (int t = 0; t < 4; ++t) st[t] = f32x4{0.f, 0.f, 0.f, 0.f};
#pragma unroll
    for (int t = 0; t < 4; ++t) {
      bf16x8 kf[4];
#pragma unroll
      for (int kc = 0; kc < 4; ++kc)
        kf[kc] = *(const bf16x8*)(Kc + (t * 16 + q16) * 128 + (((kc * 4 + g) ^ sw) << 3));
      __builtin_amdgcn_s_setprio(1);
#pragma unroll
      for (int kc = 0; kc < 4; ++kc)
        st[t] = __builtin_amdgcn_mfma_f32_16x16x32_bf16(kf[kc], qf[kc], st[t], 0, 0, 0);
      __builtin_amdgcn_s_setprio(0);
    }

    {
      float mxt = -3.0e38f;
#pragma unroll
      for (int t = 0; t < 4; ++t)
#pragma unroll
        for (int i = 0; i < 4; ++i) {
          float s = st[t][i] * SCALE;
          st[t][i] = s;
          mxt = fmaxf(mxt, s);
        }
      mxt = fmaxf(mxt, __shfl_xor(mxt, 16));
      mxt = fmaxf(mxt, __shfl_xor(mxt, 32));
      const bool keep = __all(mxt - m_run <= RESC_THR);
      const float mnew = keep ? m_run : fmaxf(m_run, mxt);
      float lsum = 0.f;
#pragma unroll
      for (int t = 0; t < 4; ++t) {
        float p0 = __expf(st[t][0] - mnew);
        float p1 = __expf(st[t][1] - mnew);
        float p2 = __expf(st[t][2] - mnew);
        float p3 = __expf(st[t][3] - mnew);
        lsum += (p0 + p1) + (p2 + p3);
        int k0 = t * 16 + g * 4;
        int a0 = q16 * 64 + ((((k0 >> 3)) ^ sw) << 3) + (k0 & 7);
        *(bf16x4*)(Plw + a0) = bf16x4{(__bf16)p0, (__bf16)p1, (__bf16)p2, (__bf16)p3};
      }
      lsum += __shfl_xor(lsum, 16);
      lsum += __shfl_xor(lsum, 32);
      if (keep) {
        l_run += lsum;
      } else {
        float alpha = __expf(m_run - mnew);
        l_run = l_run * alpha + lsum;
        m_run = mnew;
        float ar[4];
#pragma unroll
        for (int i = 0; i < 4; ++i) ar[i] = __shfl(alpha, g * 4 + i);
#pragma unroll
        for (int dc = 0; dc < 8; ++dc)
#pragma unroll
          for (int i = 0; i < 4; ++i) oacc[dc][i] *= ar[i];
      }
    }

#pragma unroll
    for (int ks = 0; ks < 2; ++ks) {
      bf16x8 pf = *(const bf16x8*)(Plw + q16 * 64 + (((ks * 4 + g) ^ sw) << 3));
      __builtin_amdgcn_s_setprio(1);
#pragma unroll
      for (int dc = 0; dc < 8; ++dc) {
        bf16x8 vf = *(const bf16x8*)(Vc + (dc * 16 + q16) * 64 + (((ks * 4 + g) ^ sw) << 3));
        oacc[dc] = __builtin_amdgcn_mfma_f32_16x16x32_bf16(pf, vf, oacc[dc], 0, 0, 0);
      }
      __builtin_amdgcn_s_setprio(0);
    }

    __syncthreads();
    cur ^= 1;
  }

  const int rowbase = (b << 10) + qt * 128 + wave * 16;
  float lr[4];
#pragma unroll
  for (int i = 0; i < 4; ++i) lr[i] = __shfl(l_run, g * 4 + i);
#pragma unroll
  for (int dc = 0; dc < 8; ++dc)
#pragma unroll
    for (int i = 0; i < 4; ++i) {
      int row = rowbase + g * 4 + i;
      int col = (h << 7) + dc * 16 + q16;
      Ob[(size_t)row * 4096 + col] = (__bf16)(oacc[dc][i] / lr[i]);
    }
#undef STAGE_KV
}

// ---------------------------------------------------------------------------
extern "C" void kernel_launch(void* const* d_in, const int* in_sizes, int n_in,
                              void* d_out, int out_size, void* d_ws,
                              size_t ws_size, hipStream_t stream) {
  const float* hidden = (const float*)d_in[0];  // [2,1024,4096] f32
  const float* cosb = (const float*)d_in[1];    // [2,1024,128] f32
  const float* sinb = (const float*)d_in[2];    // [2,1024,128] f32
  // d_in[3]: attention_mask, all-true -> ignored
  const float* w_qkv = (const float*)d_in[4];   // [6144,4096] f32
  const float* w_qn = (const float*)d_in[5];    // [128] f32
  const float* w_kn = (const float*)d_in[6];    // [128] f32
  const float* w_o = (const float*)d_in[7];     // [4096,4096] f32
  float* out = (float*)d_out;                   // [2,1024,4096] f32

  char* ws = (char*)d_ws;
  // region0 (50.3 MB): wqkvb; after QKV GEMM reused as wob (33.5) + qb (16.8)
  bf16_t* wqkvb = (bf16_t*)ws;
  bf16_t* wob = (bf16_t*)ws;
  bf16_t* qb = (bf16_t*)(ws + 33554432);
  // region1 (16.8 MB): hb; after QKV GEMM reused as attno
  bf16_t* hb = (bf16_t*)(ws + 50331648);
  bf16_t* attno = hb;
  // region2 (25.2 MB): qkv
  bf16_t* qkv = (bf16_t*)(ws + 67108864);
  // region3: kb (4.2) + vt (4.2)  -> total 100.7 MB (round-6 footprint)
  bf16_t* kb = (bf16_t*)(ws + 92274688);
  bf16_t* vt = (bf16_t*)(ws + 96468992);

  cvt_f32_bf16_2<<<dim3(16384), dim3(256), 0, stream>>>(
      hidden, hb, 8388608, w_qkv, wqkvb, 25165824);
  gemm128<3, 4, bf16_t><<<dim3(512), dim3(512), 0, stream>>>(hb, wqkvb, qkv, 2048, 6144, 4096);
  rope_scatter<<<dim3(2048), dim3(256), 0, stream>>>(qkv, cosb, sinb, w_qn, w_kn, qb, kb, vt);
  attn_fwd<<<dim3(64 * 8), dim3(512), 0, stream>>>(qb, kb, vt, attno, w_o, wob);
  gemm128<2, 4, float><<<dim3(512), dim3(512), 0, stream>>>(attno, wob, out, 2048, 4096, 4096);
}

// Round 17
// 266.333 us; speedup vs baseline: 1.2457x; 1.0006x over previous
//
#include <hip/hip_runtime.h>
#include <hip/hip_bf16.h>

typedef __bf16 bf16_t;
typedef bf16_t bf16x2 __attribute__((ext_vector_type(2)));
typedef bf16_t bf16x4 __attribute__((ext_vector_type(4)));
typedef bf16_t bf16x8 __attribute__((ext_vector_type(8)));
typedef float f32x4 __attribute__((ext_vector_type(4)));

#define DEVI __device__ __forceinline__

DEVI void gld_lds16(const void* g, void* l) {
  __builtin_amdgcn_global_load_lds(
      (const __attribute__((address_space(1))) void*)g,
      (__attribute__((address_space(3))) void*)l, 16, 0, 0);
}

// ---------------------------------------------------------------------------
// f32 -> bf16 conversion, 8 elements/thread.
// ---------------------------------------------------------------------------
__global__ __launch_bounds__(256) void cvt_f32_bf16(
    const float* __restrict__ in, bf16_t* __restrict__ out, long n) {
  long i = ((long)blockIdx.x * 256 + threadIdx.x) * 8;
  if (i >= n) return;
  float4 a = *(const float4*)(in + i);
  float4 b = *(const float4*)(in + i + 4);
  bf16x8 v = {(__bf16)a.x, (__bf16)a.y, (__bf16)a.z, (__bf16)a.w,
              (__bf16)b.x, (__bf16)b.y, (__bf16)b.z, (__bf16)b.w};
  *(bf16x8*)(out + i) = v;
}

// Two-segment variant: converts a (na elems) then b (nb elems) in one launch.
__global__ __launch_bounds__(256) void cvt_f32_bf16_2(
    const float* __restrict__ ina, bf16_t* __restrict__ outa, long na,
    const float* __restrict__ inb, bf16_t* __restrict__ outb, long nb) {
  long i = ((long)blockIdx.x * 256 + threadIdx.x) * 8;
  const float* src;
  bf16_t* dst;
  if (i < na) {
    src = ina + i;
    dst = outa + i;
  } else {
    long j = i - na;
    if (j >= nb) return;
    src = inb + j;
    dst = outb + j;
  }
  float4 a = *(const float4*)src;
  float4 b = *(const float4*)(src + 4);
  bf16x8 v = {(__bf16)a.x, (__bf16)a.y, (__bf16)a.z, (__bf16)a.w,
              (__bf16)b.x, (__bf16)b.y, (__bf16)b.z, (__bf16)b.w};
  *(bf16x8*)dst = v;
}

// ---------------------------------------------------------------------------
// Round-6-validated 128 x (64*FC) all-bf16 GEMM (92 us QKV @ FC=3, grid 512;
// ~72 us out-proj @ FC=2, grid 512).  8 waves (2M x 4N), BK=64, LDS
// double-buffered, XOR swizzle (16B slot ^ row&7) via pre-swizzled global
// source + linear LDS dest (global_load_lds).  Ledger: prologue
// T0.A+T0.B+T1.A vmcnt(2); t.p1 stage T+1.B (other buf); t.p2 stage T+2.A
// (cur buf); gate vmcnt(2) at p2, tail vmcnt(0).  XCD supertiling 2x4.
// Requires grid==nM*nN, nM%2==0, nN%4==0, K%64==0, K>=192.
// ---------------------------------------------------------------------------
template <int FC, int MINW, typename CT>
__global__ __launch_bounds__(512, MINW) void gemm128(
    const bf16_t* __restrict__ A, const bf16_t* __restrict__ W,
    CT* __restrict__ C, int M, int N, int K) {
  constexpr int BN = FC * 64;
  constexpr int P1 = FC / 2, P2 = FC - P1;
  __shared__ __align__(16) bf16_t As[2][128 * 64];
  __shared__ __align__(16) bf16_t Bs[2][BN * 64];
  const int tid = threadIdx.x, wave = tid >> 6, lane = tid & 63;
  const int q16 = lane & 15, gq = lane >> 4, sw = q16 & 7;
  const int wm = wave >> 2, wn = wave & 3;
  const int nM = M >> 7, nN = N / BN;
  const int cM = nM >> 1, cN = nN >> 2;
  const int xcd = (int)blockIdx.x & 7, wi = (int)blockIdx.x >> 3;
  const int tm = ((xcd >> 2) * cM + wi / cN) << 7;
  const int tn = ((xcd & 3) * cN + wi % cN) * BN;
  const int NT = K >> 6;
  const bf16_t* Ag = A + (size_t)tm * K;
  const bf16_t* Wg = W + (size_t)tn * K;
  const int sr = (wave << 3) + (lane >> 3);
  const int scol = (((lane & 7) ^ (sr & 7)) << 3);

#define STG(gbase, kq, uu, ldsbuf)                              \
  gld_lds16((gbase) + (size_t)((uu)*64 + sr) * K + (kq) + scol, \
            &(ldsbuf)[0] + (uu)*4096 + (wave << 9))

  f32x4 acc[4][FC];
#pragma unroll
  for (int i = 0; i < 4; ++i)
#pragma unroll
    for (int j = 0; j < FC; ++j) acc[i][j] = f32x4{0.f, 0.f, 0.f, 0.f};

  STG(Ag, 0, 0, As[0]);
  STG(Ag, 0, 1, As[0]);
#pragma unroll
  for (int u = 0; u < FC; ++u) STG(Wg, 0, u, Bs[0]);
  STG(Ag, 64, 0, As[1]);
  STG(Ag, 64, 1, As[1]);
  asm volatile("s_waitcnt vmcnt(2)" ::: "memory");
  __builtin_amdgcn_s_barrier();

  for (int t = 0; t < NT; ++t) {
    const int cur = t & 1;
    const bf16_t* Acur = As[cur];
    const bf16_t* Bcur = Bs[cur];
    const int k1 = (t + 1) << 6, k2 = (t + 2) << 6;
    bf16x8 afr[4][2];

#pragma unroll
    for (int fr = 0; fr < 4; ++fr) {
      const bf16_t* rp = Acur + (wm * 64 + fr * 16 + q16) * 64;
      afr[fr][0] = *(const bf16x8*)(rp + ((gq ^ sw) << 3));
      afr[fr][1] = *(const bf16x8*)(rp + (((4 + gq) ^ sw) << 3));
    }
    bf16x8 b1[P1][2];
#pragma unroll
    for (int fc = 0; fc < P1; ++fc) {
      const bf16_t* rp = Bcur + (wn * (16 * FC) + fc * 16 + q16) * 64;
      b1[fc][0] = *(const bf16x8*)(rp + ((gq ^ sw) << 3));
      b1[fc][1] = *(const bf16x8*)(rp + (((4 + gq) ^ sw) << 3));
    }
    if (t + 1 < NT) {
#pragma unroll
      for (int u = 0; u < FC; ++u) STG(Wg, k1, u, Bs[cur ^ 1]);
    }
    __builtin_amdgcn_s_barrier();
    __builtin_amdgcn_s_setprio(1);
#pragma unroll
    for (int fr = 0; fr < 4; ++fr)
#pragma unroll
      for (int fc = 0; fc < P1; ++fc)
#pragma unroll
        for (int kk = 0; kk < 2; ++kk)
          acc[fr][fc] = __builtin_amdgcn_mfma_f32_16x16x32_bf16(
              afr[fr][kk], b1[fc][kk], acc[fr][fc], 0, 0, 0);
    __builtin_amdgcn_s_setprio(0);
    asm volatile("" ::: "memory");
    __builtin_amdgcn_s_barrier();

    bf16x8 b2[P2][2];
#pragma unroll
    for (int f2 = 0; f2 < P2; ++f2) {
      const bf16_t* rp = Bcur + (wn * (16 * FC) + (P1 + f2) * 16 + q16) * 64;
      b2[f2][0] = *(const bf16x8*)(rp + ((gq ^ sw) << 3));
      b2[f2][1] = *(const bf16x8*)(rp + (((4 + gq) ^ sw) << 3));
    }
    if (t + 2 < NT) {
      STG(Ag, k2, 0, As[cur]);
      STG(Ag, k2, 1, As[cur]);
    }
    __builtin_amdgcn_s_barrier();
    __builtin_amdgcn_s_setprio(1);
#pragma unroll
    for (int fr = 0; fr < 4; ++fr)
#pragma unroll
      for (int f2 = 0; f2 < P2; ++f2)
#pragma unroll
        for (int kk = 0; kk < 2; ++kk)
          acc[fr][P1 + f2] = __builtin_amdgcn_mfma_f32_16x16x32_bf16(
              afr[fr][kk], b2[f2][kk], acc[fr][P1 + f2], 0, 0, 0);
    __builtin_amdgcn_s_setprio(0);
    if (t + 2 < NT)
      asm volatile("s_waitcnt vmcnt(2)" ::: "memory");
    else
      asm volatile("s_waitcnt vmcnt(0)" ::: "memory");
    __builtin_amdgcn_s_barrier();
  }

#pragma unroll
  for (int fr = 0; fr < 4; ++fr)
#pragma unroll
    for (int fc = 0; fc < FC; ++fc)
#pragma unroll
      for (int i = 0; i < 4; ++i) {
        int row = tm + wm * 64 + fr * 16 + gq * 4 + i;
        int col = tn + wn * (16 * FC) + fc * 16 + q16;
        C[(size_t)row * N + col] = (CT)acc[fr][fc][i];
      }
#undef STG
}

// ---------------------------------------------------------------------------
// RMSNorm + RoPE + scatter (unchanged, validated).
// ---------------------------------------------------------------------------
__global__ __launch_bounds__(256) void rope_scatter(
    const bf16_t* __restrict__ qkv, const float* __restrict__ cosb,
    const float* __restrict__ sinb, const float* __restrict__ wq,
    const float* __restrict__ wk, bf16_t* __restrict__ qb,
    bf16_t* __restrict__ kb, bf16_t* __restrict__ vt) {
  const int row = blockIdx.x;  // b*1024 + s
  const int b = row >> 10, s = row & 1023;
  const int wave = threadIdx.x >> 6, lane = threadIdx.x & 63;
  const int d0 = 2 * lane;
  const float c0 = cosb[(size_t)row * 128 + d0];
  const float c1 = cosb[(size_t)row * 128 + d0 + 1];
  const float s0 = sinb[(size_t)row * 128 + d0];
  const float s1 = sinb[(size_t)row * 128 + d0 + 1];
  const float g0q = wq[d0], g1q = wq[d0 + 1];
  const float g0k = wk[d0], g1k = wk[d0 + 1];
  const float sign = (lane < 32) ? -1.f : 1.f;

  for (int h = wave; h < 32; h += 4) {
    const bf16_t* x = qkv + (size_t)row * 6144 + h * 128 + d0;
    float x0 = (float)x[0], x1 = (float)x[1];
    float ss = x0 * x0 + x1 * x1;
#pragma unroll
    for (int off = 1; off < 64; off <<= 1) ss += __shfl_xor(ss, off);
    float r = rsqrtf(ss * (1.0f / 128.0f) + 1e-6f);
    float n0 = x0 * r * g0q, n1 = x1 * r * g1q;
    float o0 = __shfl_xor(n0, 32), o1 = __shfl_xor(n1, 32);
    float y0 = n0 * c0 + sign * o0 * s0;
    float y1 = n1 * c1 + sign * o1 * s1;
    bf16_t* dst = qb + ((size_t)(b * 32 + h) * 1024 + s) * 128 + d0;
    dst[0] = (__bf16)y0;
    dst[1] = (__bf16)y1;
  }
  for (int h = wave; h < 8; h += 4) {
    const bf16_t* x = qkv + (size_t)row * 6144 + 4096 + h * 128 + d0;
    float x0 = (float)x[0], x1 = (float)x[1];
    float ss = x0 * x0 + x1 * x1;
#pragma unroll
    for (int off = 1; off < 64; off <<= 1) ss += __shfl_xor(ss, off);
    float r = rsqrtf(ss * (1.0f / 128.0f) + 1e-6f);
    float n0 = x0 * r * g0k, n1 = x1 * r * g1k;
    float o0 = __shfl_xor(n0, 32), o1 = __shfl_xor(n1, 32);
    float y0 = n0 * c0 + sign * o0 * s0;
    float y1 = n1 * c1 + sign * o1 * s1;
    bf16_t* dst = kb + ((size_t)(b * 8 + h) * 1024 + s) * 128 + d0;
    dst[0] = (__bf16)y0;
    dst[1] = (__bf16)y1;
  }
  for (int h = wave; h < 8; h += 4) {
    const bf16_t* x = qkv + (size_t)row * 6144 + 5120 + h * 128 + d0;
    bf16_t* dst = vt + ((size_t)(b * 8 + h) * 128 + d0) * 1024 + s;
    dst[0] = x[0];
    dst[1024] = x[1];
  }
}

// ---------------------------------------------------------------------------
// Flash attention v6 = v5 (8 waves x 16 rows, fused w_o cvt, validated r16)
// + XCD-affinity block remap: XCD x (= bid&7) owns bh in [8x, 8x+8), so each
// XCD's K/V working set (~1-1.5MB) fits its private 4MB L2 instead of
// round-robining all 64 bh (16MB) across XCDs.  Bijective: bid -> (x, slot),
// bh = x*8 + (slot>>3), qt = slot&7.
// ---------------------------------------------------------------------------
__global__ __launch_bounds__(512, 4) void attn_fwd(
    const bf16_t* __restrict__ Qb, const bf16_t* __restrict__ Kb,
    const bf16_t* __restrict__ Vt, bf16_t* __restrict__ Ob,
    const float* __restrict__ wo_src, bf16_t* __restrict__ wo_dst) {
  __shared__ __align__(16) bf16_t Kl[2][64 * 128];
  __shared__ __align__(16) bf16_t Vl[2][128 * 64];
  __shared__ __align__(16) bf16_t Pl[8][16 * 64];
  const int tid = threadIdx.x, wave = tid >> 6, lane = tid & 63;
  const int q16 = lane & 15, g = lane >> 4;
  const int bid = blockIdx.x;
  // XCD-affinity remap (bijective on [0,512))
  const int xcd8 = bid & 7, slot = bid >> 3;
  const int bh = xcd8 * 8 + (slot >> 3), qt = slot & 7;
  const int b = bh >> 5, h = bh & 31;
  const int kvh = (b << 3) + (h >> 2);
  const bf16_t* qp = Qb + ((size_t)bh * 1024 + qt * 128 + wave * 16) * 128;
  const bf16_t* kp = Kb + (size_t)kvh * (1024 * 128);
  const bf16_t* vp = Vt + (size_t)kvh * (128 * 1024);
  const float SCALE = 0.088388347648318447f;
  const float RESC_THR = 8.0f;
  const int sw = q16 & 7;

  bf16x8 qf[4];
#pragma unroll
  for (int kc = 0; kc < 4; ++kc)
    qf[kc] = *(const bf16x8*)(qp + q16 * 128 + kc * 32 + g * 8);

  f32x4 oacc[8];
#pragma unroll
  for (int dc = 0; dc < 8; ++dc) oacc[dc] = f32x4{0.f, 0.f, 0.f, 0.f};
  float m_run = -3.0e38f, l_run = 0.f;

#define STAGE_KV(buf, jj)                                                      \
  {                                                                            \
    _Pragma("unroll") for (int i = 0; i < 2; ++i) {                            \
      int n = (wave * 2 + i) * 64 + lane;                                      \
      int rk = n >> 4, ck = (n & 15) ^ (rk & 7);                               \
      gld_lds16(kp + (size_t)((jj) + rk) * 128 + ck * 8,                       \
                &Kl[buf][0] + (wave * 2 + i) * 512);                           \
      int rv = n >> 3, cv = (n & 7) ^ (rv & 7);                                \
      gld_lds16(vp + (size_t)rv * 1024 + (jj) + cv * 8,                        \
                &Vl[buf][0] + (wave * 2 + i) * 512);                           \
    }                                                                          \
  }

  STAGE_KV(0, 0);
  __syncthreads();
  int cur = 0;

  for (int jt = 0; jt < 16; ++jt) {
    if (jt < 15) STAGE_KV(cur ^ 1, (jt + 1) * 64);

    // fused w_o convert: one float4 in, one bf16x4 out per thread per tile.
    {
      long ci = (((long)bid * 16 + jt) * 512 + tid) * 4;
      float4 w4 = *(const float4*)(wo_src + ci);
      *(bf16x4*)(wo_dst + ci) =
          bf16x4{(__bf16)w4.x, (__bf16)w4.y, (__bf16)w4.z, (__bf16)w4.w};
    }

    const bf16_t* Kc = &Kl[cur][0];
    const bf16_t* Vc = &Vl[cur][0];
    bf16_t* Plw = &Pl[wave][0];

    f32x4 st[4];
#pragma unroll
    for (int t = 0; t < 4; ++t) st[t] = f32x4{0.f, 0.f, 0.f, 0.f};
#pragma unroll
    for (int t = 0; t < 4; ++t) {
      bf16x8 kf[4];
#pragma unroll
      for (int kc = 0; kc < 4; ++kc)
        kf[kc] = *(const bf16x8*)(Kc + (t * 16 + q16) * 128 + (((kc * 4 + g) ^ sw) << 3));
      __builtin_amdgcn_s_setprio(1);
#pragma unroll
      for (int kc = 0; kc < 4; ++kc)
        st[t] = __builtin_amdgcn_mfma_f32_16x16x32_bf16(kf[kc], qf[kc], st[t], 0, 0, 0);
      __builtin_amdgcn_s_setprio(0);
    }

    {
      float mxt = -3.0e38f;
#pragma unroll
      for (int t = 0; t < 4; ++t)
#pragma unroll
        for (int i = 0; i < 4; ++i) {
          float s = st[t][i] * SCALE;
          st[t][i] = s;
          mxt = fmaxf(mxt, s);
        }
      mxt = fmaxf(mxt, __shfl_xor(mxt, 16));
      mxt = fmaxf(mxt, __shfl_xor(mxt, 32));
      const bool keep = __all(mxt - m_run <= RESC_THR);
      const float mnew = keep ? m_run : fmaxf(m_run, mxt);
      float lsum = 0.f;
#pragma unroll
      for (int t = 0; t < 4; ++t) {
        float p0 = __expf(st[t][0] - mnew);
        float p1 = __expf(st[t][1] - mnew);
        float p2 = __expf(st[t][2] - mnew);
        float p3 = __expf(st[t][3] - mnew);
        lsum += (p0 + p1) + (p2 + p3);
        int k0 = t * 16 + g * 4;
        int a0 = q16 * 64 + ((((k0 >> 3)) ^ sw) << 3) + (k0 & 7);
        *(bf16x4*)(Plw + a0) = bf16x4{(__bf16)p0, (__bf16)p1, (__bf16)p2, (__bf16)p3};
      }
      lsum += __shfl_xor(lsum, 16);
      lsum += __shfl_xor(lsum, 32);
      if (keep) {
        l_run += lsum;
      } else {
        float alpha = __expf(m_run - mnew);
        l_run = l_run * alpha + lsum;
        m_run = mnew;
        float ar[4];
#pragma unroll
        for (int i = 0; i < 4; ++i) ar[i] = __shfl(alpha, g * 4 + i);
#pragma unroll
        for (int dc = 0; dc < 8; ++dc)
#pragma unroll
          for (int i = 0; i < 4; ++i) oacc[dc][i] *= ar[i];
      }
    }

#pragma unroll
    for (int ks = 0; ks < 2; ++ks) {
      bf16x8 pf = *(const bf16x8*)(Plw + q16 * 64 + (((ks * 4 + g) ^ sw) << 3));
      __builtin_amdgcn_s_setprio(1);
#pragma unroll
      for (int dc = 0; dc < 8; ++dc) {
        bf16x8 vf = *(const bf16x8*)(Vc + (dc * 16 + q16) * 64 + (((ks * 4 + g) ^ sw) << 3));
        oacc[dc] = __builtin_amdgcn_mfma_f32_16x16x32_bf16(pf, vf, oacc[dc], 0, 0, 0);
      }
      __builtin_amdgcn_s_setprio(0);
    }

    __syncthreads();
    cur ^= 1;
  }

  const int rowbase = (b << 10) + qt * 128 + wave * 16;
  float lr[4];
#pragma unroll
  for (int i = 0; i < 4; ++i) lr[i] = __shfl(l_run, g * 4 + i);
#pragma unroll
  for (int dc = 0; dc < 8; ++dc)
#pragma unroll
    for (int i = 0; i < 4; ++i) {
      int row = rowbase + g * 4 + i;
      int col = (h << 7) + dc * 16 + q16;
      Ob[(size_t)row * 4096 + col] = (__bf16)(oacc[dc][i] / lr[i]);
    }
#undef STAGE_KV
}

// ---------------------------------------------------------------------------
extern "C" void kernel_launch(void* const* d_in, const int* in_sizes, int n_in,
                              void* d_out, int out_size, void* d_ws,
                              size_t ws_size, hipStream_t stream) {
  const float* hidden = (const float*)d_in[0];  // [2,1024,4096] f32
  const float* cosb = (const float*)d_in[1];    // [2,1024,128] f32
  const float* sinb = (const float*)d_in[2];    // [2,1024,128] f32
  // d_in[3]: attention_mask, all-true -> ignored
  const float* w_qkv = (const float*)d_in[4];   // [6144,4096] f32
  const float* w_qn = (const float*)d_in[5];    // [128] f32
  const float* w_kn = (const float*)d_in[6];    // [128] f32
  const float* w_o = (const float*)d_in[7];     // [4096,4096] f32
  float* out = (float*)d_out;                   // [2,1024,4096] f32

  char* ws = (char*)d_ws;
  // region0 (50.3 MB): wqkvb; after QKV GEMM reused as wob (33.5) + qb (16.8)
  bf16_t* wqkvb = (bf16_t*)ws;
  bf16_t* wob = (bf16_t*)ws;
  bf16_t* qb = (bf16_t*)(ws + 33554432);
  // region1 (16.8 MB): hb; after QKV GEMM reused as attno
  bf16_t* hb = (bf16_t*)(ws + 50331648);
  bf16_t* attno = hb;
  // region2 (25.2 MB): qkv
  bf16_t* qkv = (bf16_t*)(ws + 67108864);
  // region3: kb (4.2) + vt (4.2)  -> total 100.7 MB (round-6 footprint)
  bf16_t* kb = (bf16_t*)(ws + 92274688);
  bf16_t* vt = (bf16_t*)(ws + 96468992);

  cvt_f32_bf16_2<<<dim3(16384), dim3(256), 0, stream>>>(
      hidden, hb, 8388608, w_qkv, wqkvb, 25165824);
  gemm128<3, 4, bf16_t><<<dim3(512), dim3(512), 0, stream>>>(hb, wqkvb, qkv, 2048, 6144, 4096);
  rope_scatter<<<dim3(2048), dim3(256), 0, stream>>>(qkv, cosb, sinb, w_qn, w_kn, qb, kb, vt);
  attn_fwd<<<dim3(64 * 8), dim3(512), 0, stream>>>(qb, kb, vt, attno, w_o, wob);
  gemm128<2, 4, float><<<dim3(512), dim3(512), 0, stream>>>(attno, wob, out, 2048, 4096, 4096);
}